// Round 1
// 229.591 us; speedup vs baseline: 1.2572x; 1.2572x over previous
//
#include <hip/hip_runtime.h>

#define IN_DIM   128
#define OUT_DIM  128
#define ATTN_DIM 64
#define N_RELV   401
#define N_NODE   50000
#define N_EDGE   500000
#define N_QUERY  64
#define N_DT     731
#define CAP      40       // padded bucket capacity (deg ~ Poisson(10); P(>=40) ~ 1e-11)

typedef unsigned short ushort_t;
typedef unsigned int   uint_t;
typedef __attribute__((ext_vector_type(8))) short v8s;   // 8 bf16 (4 VGPRs)
typedef __attribute__((ext_vector_type(4))) float v4f;

__device__ __forceinline__ int clampi(int v, int lo, int hi) {
    return v < lo ? lo : (v > hi ? hi : v);
}
__device__ __forceinline__ float bu2f(ushort_t u) {
    union { uint_t i; float f; } v; v.i = ((uint_t)u) << 16; return v.f;
}
__device__ __forceinline__ float blo(uint_t u) { return bu2f((ushort_t)(u & 0xffff)); }
__device__ __forceinline__ float bhi(uint_t u) { return bu2f((ushort_t)(u >> 16)); }
__device__ __forceinline__ ushort_t f2bu(float f) {   // RNE, finite inputs
    union { float f; uint_t i; } v; v.f = f;
    const uint_t x = v.i;
    return (ushort_t)((x + 0x7fffu + ((x >> 16) & 1u)) >> 16);
}

// edge parse (int32 vs int64 rows)
__device__ __forceinline__ void parse_edge(const int* __restrict__ edges, int e,
                                           int i64, int& r, int& rel, int& tau,
                                           int& sub, int& obj) {
    if (i64) {
        const int* E = edges + (size_t)e * 14;
        r = E[0]; rel = E[4]; tau = E[8]; sub = E[10]; obj = E[12];
    } else {
        const int* E = edges + (size_t)e * 7;
        r = E[0]; rel = E[2]; tau = E[4]; sub = E[5]; obj = E[6];
    }
    r   = clampi(r,   0, N_QUERY - 1);
    rel = clampi(rel, 0, N_RELV - 1);
    sub = clampi(sub, 0, N_NODE - 1);
    obj = clampi(obj, 0, N_NODE - 1);
}

// ---------------------------------------------------------------------------
// Fused one-time prep: WTb build + int64-detect + cnt/ovf zero.
//   WTb[n][k] = bf16( n<64 ? Ws[k][n] : Wh[k][n-64] )   (192 x 128)
// ---------------------------------------------------------------------------
__global__ __launch_bounds__(256) void prep_kernel(
    const int* __restrict__ edges, const float* __restrict__ Ws,
    const float* __restrict__ Wh, ushort_t* __restrict__ WTb,
    int* __restrict__ flag, int* __restrict__ cnt, int* __restrict__ ovfn)
{
    const int i = blockIdx.x * 256 + threadIdx.x;   // 96*256 = 24576 exact
    const int n = i >> 7, k = i & 127;
    const float w = (n < 64) ? Ws[k * 64 + n] : Wh[k * 128 + (n - 64)];
    WTb[i] = f2bu(w);

    for (int idx = i; idx < N_NODE; idx += 96 * 256) cnt[idx] = 0;
    if (i == 0) ovfn[0] = 0;

    if (blockIdx.x == 0) {
        __shared__ int bad;
        if (threadIdx.x == 0) bad = 0;
        __syncthreads();
        for (int t = threadIdx.x; t < 1000; t += 256) {
            const int w32 = edges[2 * t + 1];
            if (w32 != 0 && w32 != -1) bad = 1;
        }
        __syncthreads();
        if (threadIdx.x == 0) flag[0] = (bad == 0) ? 1 : 0;
    }
}

// ---------------------------------------------------------------------------
// MFMA node projection with SWAPPED operands (A = weights, B = hidden):
// D[row=outdim][col=node]; each lane holds 4 consecutive dims of ONE node
// -> one packed 8-B store per 16x16 tile instead of 4 scattered 2-B stores.
// ---------------------------------------------------------------------------
__global__ __launch_bounds__(256) void node_tab_mfma(
    const float* __restrict__ hidden, const ushort_t* __restrict__ WTb,
    ushort_t* __restrict__ node_attn, ushort_t* __restrict__ node_msg)
{
    const int tid  = threadIdx.x;
    const int wid  = tid >> 6;
    const int lane = tid & 63;
    const int m16  = lane & 15;
    const int q    = lane >> 4;
    const int nb   = blockIdx.x * 64;
    const int row  = nb + wid * 16 + m16;               // this lane's node
    const int rowc = row < N_NODE ? row : N_NODE - 1;   // tail clamp

    v8s hfr[4];   // B-operand fragments: hidden[node=m16][k-chunk 8q+32c]
    #pragma unroll
    for (int c = 0; c < 4; ++c) {
        const float4 f0 = *(const float4*)(hidden + (size_t)rowc * 128 + 32 * c + 8 * q);
        const float4 f1 = *(const float4*)(hidden + (size_t)rowc * 128 + 32 * c + 8 * q + 4);
        v8s a;
        a[0] = (short)f2bu(f0.x); a[1] = (short)f2bu(f0.y);
        a[2] = (short)f2bu(f0.z); a[3] = (short)f2bu(f0.w);
        a[4] = (short)f2bu(f1.x); a[5] = (short)f2bu(f1.y);
        a[6] = (short)f2bu(f1.z); a[7] = (short)f2bu(f1.w);
        hfr[c] = a;
    }

    #pragma unroll
    for (int t = 0; t < 12; ++t) {
        v4f acc = {0.f, 0.f, 0.f, 0.f};
        #pragma unroll
        for (int c = 0; c < 4; ++c) {
            // A-operand: W fragment, row = outdim offset m16, k-chunk 8q+32c
            const v8s wfr = *(const v8s*)(WTb + (size_t)(16 * t + m16) * 128 + 32 * c + 8 * q);
            acc = __builtin_amdgcn_mfma_f32_16x16x32_bf16(wfr, hfr[c], acc, 0, 0, 0);
        }
        if (row < N_NODE) {
            // lane's D entries: node=row, dims 16t+4q .. +3  -> pack 2x bf16x2
            const uint_t u0 = (uint_t)f2bu(acc[0]) | ((uint_t)f2bu(acc[1]) << 16);
            const uint_t u1 = (uint_t)f2bu(acc[2]) | ((uint_t)f2bu(acc[3]) << 16);
            const int dim = 16 * t + 4 * q;
            if (dim < 64) {
                uint2* dst = (uint2*)(node_attn + (size_t)row * 64 + dim);
                *dst = make_uint2(u0, u1);
            } else {
                uint2* dst = (uint2*)(node_msg + (size_t)row * 128 + (dim - 64));
                *dst = make_uint2(u0, u1);
            }
        }
    }
}

// ---------------------------------------------------------------------------
// Fused small tables: rel (401 blocks) | dt (731 blocks) | qr (64 blocks)
// ---------------------------------------------------------------------------
__global__ __launch_bounds__(128) void tables_kernel(
    const float* __restrict__ rela, const float* __restrict__ Wr,
    const float* __restrict__ Wtau, const float* __restrict__ Wh,
    const float* __restrict__ wt1, const float* __restrict__ bt1,
    const float* __restrict__ wt2, const float* __restrict__ bt2,
    const int* __restrict__ q_rel, const float* __restrict__ WqrW,
    const float* __restrict__ Wqrb, const int* __restrict__ flag,
    ushort_t* __restrict__ rel_attn, ushort_t* __restrict__ rel_msg,
    ushort_t* __restrict__ dt_attn,  ushort_t* __restrict__ dt_msg,
    ushort_t* __restrict__ Xqr)
{
    const int b = blockIdx.x, tid = threadIdx.x;
    __shared__ float h[IN_DIM];

    if (b < N_RELV) {
        const int r = b;
        h[tid] = rela[(size_t)r * IN_DIM + tid];
        __syncthreads();
        if (tid < ATTN_DIM) {
            float a = 0.f;
            #pragma unroll 8
            for (int d = 0; d < IN_DIM; ++d) a += h[d] * Wr[d * ATTN_DIM + tid];
            rel_attn[(size_t)r * ATTN_DIM + tid] = f2bu(a);
        }
        float m = 0.f;
        #pragma unroll 8
        for (int d = 0; d < IN_DIM; ++d) m += h[d] * Wh[d * OUT_DIM + tid];
        rel_msg[(size_t)r * OUT_DIM + tid] = f2bu(m);
    } else if (b < N_RELV + N_DT) {
        const int i = b - N_RELV;
        const float dt = (float)(i - 365);
        h[tid] = wt1[tid] * dt + bt1[tid] + sinf(wt2[tid] * dt + bt2[tid]);
        __syncthreads();
        if (tid < ATTN_DIM) {
            float a = 0.f;
            #pragma unroll 8
            for (int d = 0; d < IN_DIM; ++d) a += h[d] * Wtau[d * ATTN_DIM + tid];
            dt_attn[(size_t)i * ATTN_DIM + tid] = f2bu(a);
        }
        float m = 0.f;
        #pragma unroll 8
        for (int d = 0; d < IN_DIM; ++d) m += h[d] * Wh[d * OUT_DIM + tid];
        dt_msg[(size_t)i * OUT_DIM + tid] = f2bu(m);
    } else {
        const int qn  = b - N_RELV - N_DT;
        const int i64 = flag[0];
        const int rel = clampi(q_rel[i64 ? 2 * qn : qn], 0, N_RELV - 1);
        h[tid] = rela[(size_t)rel * IN_DIM + tid];
        __syncthreads();
        if (tid < ATTN_DIM) {
            float acc = Wqrb[tid];
            #pragma unroll 8
            for (int d = 0; d < IN_DIM; ++d) acc += h[d] * WqrW[d * ATTN_DIM + tid];
            Xqr[(size_t)qn * ATTN_DIM + tid] = f2bu(acc);
        }
    }
}

// ---------------------------------------------------------------------------
// Phase 1: per-edge alpha, 8 lanes/edge, padded-bucket scatter (single int4).
// ---------------------------------------------------------------------------
__global__ __launch_bounds__(256) void alpha_scatter(
    const int* __restrict__ edges, const int* __restrict__ q_tau,
    const ushort_t* __restrict__ node_attn, const ushort_t* __restrict__ rel_attn,
    const ushort_t* __restrict__ dt_attn,  const ushort_t* __restrict__ Xqr,
    const float* __restrict__ w_alpha_W, const float* __restrict__ w_alpha_b,
    const int* __restrict__ flag, int* __restrict__ cnt,
    int4* __restrict__ meta, int* __restrict__ ovfn, int4* __restrict__ ovfl)
{
    const int g   = threadIdx.x & 7;
    const int e   = blockIdx.x * 32 + (threadIdx.x >> 3);   // 500000/32 = 15625
    const int i64 = flag[0];

    int r, rel, tau, sub, obj;
    parse_edge(edges, e, i64, r, rel, tau, sub, obj);
    const int tq = q_tau[i64 ? 2 * r : r];
    if (tau < 0) tau = tq;
    const int di = clampi(tau - tq + 365, 0, N_DT - 1);

    const uint4 xs = *(const uint4*)(node_attn + (size_t)sub * ATTN_DIM + 8 * g);
    const uint4 xr = *(const uint4*)(rel_attn + (size_t)rel * ATTN_DIM + 8 * g);
    const uint4 xt = *(const uint4*)(dt_attn  + (size_t)di  * ATTN_DIM + 8 * g);
    const uint4 xq = *(const uint4*)(Xqr      + (size_t)r   * ATTN_DIM + 8 * g);
    const float4 wA = *(const float4*)(w_alpha_W + 8 * g);
    const float4 wB = *(const float4*)(w_alpha_W + 8 * g + 4);

    float s0, s1, v;
    s0 = blo(xs.x) + blo(xr.x) + blo(xt.x) + blo(xq.x);
    s1 = bhi(xs.x) + bhi(xr.x) + bhi(xt.x) + bhi(xq.x);
    v  = fmaxf(s0, 0.f) * wA.x + fmaxf(s1, 0.f) * wA.y;
    s0 = blo(xs.y) + blo(xr.y) + blo(xt.y) + blo(xq.y);
    s1 = bhi(xs.y) + bhi(xr.y) + bhi(xt.y) + bhi(xq.y);
    v += fmaxf(s0, 0.f) * wA.z + fmaxf(s1, 0.f) * wA.w;
    s0 = blo(xs.z) + blo(xr.z) + blo(xt.z) + blo(xq.z);
    s1 = bhi(xs.z) + bhi(xr.z) + bhi(xt.z) + bhi(xq.z);
    v += fmaxf(s0, 0.f) * wB.x + fmaxf(s1, 0.f) * wB.y;
    s0 = blo(xs.w) + blo(xr.w) + blo(xt.w) + blo(xq.w);
    s1 = bhi(xs.w) + bhi(xr.w) + bhi(xt.w) + bhi(xq.w);
    v += fmaxf(s0, 0.f) * wB.z + fmaxf(s1, 0.f) * wB.w;

    v += __shfl_down(v, 4, 8);
    v += __shfl_down(v, 2, 8);
    v += __shfl_down(v, 1, 8);

    if (g == 0) {
        const float alpha = 1.f / (1.f + __expf(-(v + w_alpha_b[0])));
        const int pos = atomicAdd(&cnt[obj], 1);
        if (pos < CAP) {
            meta[(size_t)obj * CAP + pos] =
                make_int4(sub | (di << 17), rel, __float_as_int(alpha), 0);
        } else {
            const int ov = atomicAdd(ovfn, 1);
            if (ov < N_EDGE)
                ovfl[ov] = make_int4(sub | (di << 17), rel | (obj << 9),
                                     __float_as_int(alpha), 0);
        }
    }
}

// ---------------------------------------------------------------------------
// Phase 2: per-node aggregation from padded buckets, no atomics.
// ---------------------------------------------------------------------------
__device__ __forceinline__ void agg_step(
    int4 m, int lane,
    const ushort_t* __restrict__ node_msg, const ushort_t* __restrict__ rel_msg,
    const ushort_t* __restrict__ dt_msg, float& a0, float& a1)
{
    const int sub = m.x & 0x1FFFF;
    const int di  = (int)(((uint_t)m.x) >> 17);
    const int rel = m.y;
    const float al = __int_as_float(m.z);
    const uint_t am = *(const uint_t*)(node_msg + (size_t)sub * 128 + 2 * lane);
    const uint_t bm = *(const uint_t*)(rel_msg  + (size_t)rel * 128 + 2 * lane);
    const uint_t tm = *(const uint_t*)(dt_msg   + (size_t)di  * 128 + 2 * lane);
    a0 += al * (blo(am) + blo(bm) + blo(tm));
    a1 += al * (bhi(am) + bhi(bm) + bhi(tm));
}

__global__ __launch_bounds__(256) void agg_kernel(
    const int* __restrict__ cnt, const int4* __restrict__ meta,
    const ushort_t* __restrict__ node_msg, const ushort_t* __restrict__ rel_msg,
    const ushort_t* __restrict__ dt_msg, float* __restrict__ out)
{
    const int lane = threadIdx.x & 63;
    const int n    = blockIdx.x * 4 + (threadIdx.x >> 6);

    int m = cnt[n]; if (m > CAP) m = CAP;
    const int4* row = meta + (size_t)n * CAP;
    float a0 = 0.f, a1 = 0.f;
    int j = 0;
    for (; j + 1 < m; j += 2) {
        const int4 m0 = row[j];
        const int4 m1 = row[j + 1];
        agg_step(m0, lane, node_msg, rel_msg, dt_msg, a0, a1);
        agg_step(m1, lane, node_msg, rel_msg, dt_msg, a0, a1);
    }
    if (j < m)
        agg_step(row[j], lane, node_msg, rel_msg, dt_msg, a0, a1);

    ((float2*)(out + (size_t)n * OUT_DIM))[lane] = make_float2(a0, a1);
}

// ---------------------------------------------------------------------------
// Overflow fix-up (normally empty): atomically add overflowed edges into out.
// ---------------------------------------------------------------------------
__global__ __launch_bounds__(256) void ovf_fix(
    const int* __restrict__ ovfn, const int4* __restrict__ ovfl,
    const ushort_t* __restrict__ node_msg, const ushort_t* __restrict__ rel_msg,
    const ushort_t* __restrict__ dt_msg, float* __restrict__ out)
{
    const int lane = threadIdx.x & 63;
    int nov = ovfn[0]; if (nov > N_EDGE) nov = N_EDGE;
    for (int i = blockIdx.x * 4 + (threadIdx.x >> 6); i < nov; i += 64 * 4) {
        const int4 m = ovfl[i];
        const int sub = m.x & 0x1FFFF;
        const int di  = (int)(((uint_t)m.x) >> 17);
        const int rel = m.y & 0x1FF;
        const int obj = (int)(((uint_t)m.y) >> 9);
        const float al = __int_as_float(m.z);
        const uint_t am = *(const uint_t*)(node_msg + (size_t)sub * 128 + 2 * lane);
        const uint_t bm = *(const uint_t*)(rel_msg  + (size_t)rel * 128 + 2 * lane);
        const uint_t tm = *(const uint_t*)(dt_msg   + (size_t)di  * 128 + 2 * lane);
        float* dst = out + (size_t)obj * OUT_DIM;
        atomicAdd(dst + 2 * lane,     al * (blo(am) + blo(bm) + blo(tm)));
        atomicAdd(dst + 2 * lane + 1, al * (bhi(am) + bhi(bm) + bhi(tm)));
    }
}

// ---------------------------------------------------------------------------
// Fallback: single-pass atomic edge kernel (small-workspace path).
// ---------------------------------------------------------------------------
__global__ __launch_bounds__(256) void edge_atomic_kernel(
    const int* __restrict__ edges, const int* __restrict__ q_tau,
    const ushort_t* __restrict__ node_attn, const ushort_t* __restrict__ node_msg,
    const ushort_t* __restrict__ rel_attn,  const ushort_t* __restrict__ rel_msg,
    const ushort_t* __restrict__ dt_attn,   const ushort_t* __restrict__ dt_msg,
    const ushort_t* __restrict__ Xqr,
    const float* __restrict__ w_alpha_W, const float* __restrict__ w_alpha_b,
    const int* __restrict__ flag, float* __restrict__ out)
{
    const int lane = threadIdx.x & 63;
    const int e    = blockIdx.x * 4 + (threadIdx.x >> 6);
    const int i64  = flag[0];

    int r, rel, tau, sub, obj;
    parse_edge(edges, e, i64, r, rel, tau, sub, obj);
    const int tq = q_tau[i64 ? 2 * r : r];
    if (tau < 0) tau = tq;
    const int di = clampi(tau - tq + 365, 0, N_DT - 1);

    const float xs = bu2f(node_attn[(size_t)sub * ATTN_DIM + lane]);
    const float xr = bu2f(rel_attn[(size_t)rel * ATTN_DIM + lane]);
    const float xt = bu2f(dt_attn[(size_t)di  * ATTN_DIM + lane]);
    const float xq = bu2f(Xqr[(size_t)r * ATTN_DIM + lane]);

    float v = fmaxf(xs + xr + xq + xt, 0.f) * w_alpha_W[lane];
    #pragma unroll
    for (int off = 32; off > 0; off >>= 1)
        v += __shfl_down(v, off, 64);
    v = __shfl(v, 0, 64);
    const float alpha = 1.f / (1.f + __expf(-(v + w_alpha_b[0])));

    const uint_t am = *(const uint_t*)(node_msg + (size_t)sub * 128 + 2 * lane);
    const uint_t bm = *(const uint_t*)(rel_msg  + (size_t)rel * 128 + 2 * lane);
    const uint_t tm = *(const uint_t*)(dt_msg   + (size_t)di  * 128 + 2 * lane);
    const float mx = blo(am) + blo(bm) + blo(tm);
    const float my = bhi(am) + bhi(bm) + bhi(tm);

    float* dst = out + (size_t)obj * OUT_DIM;
    atomicAdd(dst + 2 * lane,     alpha * mx);
    atomicAdd(dst + 2 * lane + 1, alpha * my);
}

// ===========================================================================
extern "C" void kernel_launch(void* const* d_in, const int* in_sizes, int n_in,
                              void* d_out, int out_size, void* d_ws, size_t ws_size,
                              hipStream_t stream)
{
    const int*   q_rel  = (const int*)d_in[1];
    const int*   q_tau  = (const int*)d_in[2];
    const float* hidden = (const float*)d_in[3];
    const int*   edges  = (const int*)d_in[4];
    const float* rela   = (const float*)d_in[7];
    const float* Ws     = (const float*)d_in[8];
    const float* Wr     = (const float*)d_in[9];
    const float* WqrW   = (const float*)d_in[10];
    const float* Wqrb   = (const float*)d_in[11];
    const float* Wtau   = (const float*)d_in[12];
    const float* waW    = (const float*)d_in[13];
    const float* wab    = (const float*)d_in[14];
    const float* Wh     = (const float*)d_in[15];
    const float* wt1    = (const float*)d_in[16];
    const float* bt1    = (const float*)d_in[17];
    const float* wt2    = (const float*)d_in[18];
    const float* bt2    = (const float*)d_in[19];
    float* out = (float*)d_out;

    // --- workspace carve (256-B aligned chunks); base region first ---
    char* p = (char*)d_ws;
    size_t off = 0;
    auto carve = [&](size_t bytes) {
        char* q = p + off;
        off = (off + bytes + 255) & ~(size_t)255;
        return q;
    };
    int*      flag      = (int*)     carve(64);
    int*      cnt       = (int*)     carve((size_t)N_NODE * 4);
    int*      ovfn      = (int*)     carve(64);
    ushort_t* WTb       = (ushort_t*)carve((size_t)192 * 128 * 2);
    ushort_t* XqrB      = (ushort_t*)carve((size_t)N_QUERY * ATTN_DIM * 2);
    ushort_t* rel_attn  = (ushort_t*)carve((size_t)N_RELV * ATTN_DIM * 2);
    ushort_t* rel_msg   = (ushort_t*)carve((size_t)N_RELV * OUT_DIM * 2);
    ushort_t* dt_attn   = (ushort_t*)carve((size_t)N_DT * ATTN_DIM * 2);
    ushort_t* dt_msg    = (ushort_t*)carve((size_t)N_DT * OUT_DIM * 2);
    ushort_t* node_attn = (ushort_t*)carve((size_t)N_NODE * ATTN_DIM * 2);
    ushort_t* node_msg  = (ushort_t*)carve((size_t)N_NODE * OUT_DIM * 2);
    int4*     meta      = (int4*)    carve((size_t)N_NODE * CAP * 16);
    int4*     ovfl      = (int4*)    carve((size_t)N_EDGE * 16);
    const size_t need_full = off;

    // shared precompute (both paths)
    prep_kernel<<<96, 256, 0, stream>>>(edges, Ws, Wh, WTb, flag, cnt, ovfn);
    tables_kernel<<<N_RELV + N_DT + N_QUERY, 128, 0, stream>>>(
        rela, Wr, Wtau, Wh, wt1, bt1, wt2, bt2, q_rel, WqrW, Wqrb, flag,
        rel_attn, rel_msg, dt_attn, dt_msg, XqrB);
    node_tab_mfma<<<(N_NODE + 63) / 64, 256, 0, stream>>>(hidden, WTb,
                                                          node_attn, node_msg);

    if (ws_size >= need_full) {
        alpha_scatter<<<N_EDGE / 32, 256, 0, stream>>>(edges, q_tau, node_attn,
                                                       rel_attn, dt_attn, XqrB,
                                                       waW, wab, flag, cnt,
                                                       meta, ovfn, ovfl);
        agg_kernel<<<N_NODE / 4, 256, 0, stream>>>(cnt, meta, node_msg,
                                                   rel_msg, dt_msg, out);
        ovf_fix<<<64, 256, 0, stream>>>(ovfn, ovfl, node_msg, rel_msg,
                                        dt_msg, out);
    } else {
        (void)hipMemsetAsync(out, 0, (size_t)out_size * sizeof(float), stream);
        edge_atomic_kernel<<<N_EDGE / 4, 256, 0, stream>>>(edges, q_tau,
                                                           node_attn, node_msg,
                                                           rel_attn, rel_msg,
                                                           dt_attn, dt_msg, XqrB,
                                                           waW, wab, flag, out);
    }
}

// Round 2
// 217.134 us; speedup vs baseline: 1.3293x; 1.0574x over previous
//
#include <hip/hip_runtime.h>
#include <hip/hip_fp16.h>

#define IN_DIM   128
#define OUT_DIM  128
#define ATTN_DIM 64
#define N_RELV   401
#define N_NODE   50000
#define N_EDGE   500000
#define N_QUERY  64
#define N_DT     731
#define CAP      40       // padded bucket capacity (deg ~ Poisson(10); P(>=40) ~ 1e-11)

typedef unsigned short ushort_t;
typedef unsigned int   uint_t;
typedef __attribute__((ext_vector_type(8))) short v8s;   // 8 bf16 (4 VGPRs)
typedef __attribute__((ext_vector_type(4))) float v4f;

__device__ __forceinline__ int clampi(int v, int lo, int hi) {
    return v < lo ? lo : (v > hi ? hi : v);
}
__device__ __forceinline__ float bu2f(ushort_t u) {
    union { uint_t i; float f; } v; v.i = ((uint_t)u) << 16; return v.f;
}
__device__ __forceinline__ float blo(uint_t u) { return bu2f((ushort_t)(u & 0xffff)); }
__device__ __forceinline__ float bhi(uint_t u) { return bu2f((ushort_t)(u >> 16)); }
__device__ __forceinline__ ushort_t f2bu(float f) {   // RNE, finite inputs
    union { float f; uint_t i; } v; v.f = f;
    const uint_t x = v.i;
    return (ushort_t)((x + 0x7fffu + ((x >> 16) & 1u)) >> 16);
}

// edge parse (int32 vs int64 rows)
__device__ __forceinline__ void parse_edge(const int* __restrict__ edges, int e,
                                           int i64, int& r, int& rel, int& tau,
                                           int& sub, int& obj) {
    if (i64) {
        const int* E = edges + (size_t)e * 14;
        r = E[0]; rel = E[4]; tau = E[8]; sub = E[10]; obj = E[12];
    } else {
        const int* E = edges + (size_t)e * 7;
        r = E[0]; rel = E[2]; tau = E[4]; sub = E[5]; obj = E[6];
    }
    r   = clampi(r,   0, N_QUERY - 1);
    rel = clampi(rel, 0, N_RELV - 1);
    sub = clampi(sub, 0, N_NODE - 1);
    obj = clampi(obj, 0, N_NODE - 1);
}

// ---------------------------------------------------------------------------
// Fused one-time prep: WTb build + int64-detect + cnt/ovf zero.
//   WTb[n][k] = bf16( n<64 ? Ws[k][n] : Wh[k][n-64] )   (192 x 128)
// ---------------------------------------------------------------------------
__global__ __launch_bounds__(256) void prep_kernel(
    const int* __restrict__ edges, const float* __restrict__ Ws,
    const float* __restrict__ Wh, ushort_t* __restrict__ WTb,
    int* __restrict__ flag, int* __restrict__ cnt, int* __restrict__ ovfn)
{
    const int i = blockIdx.x * 256 + threadIdx.x;   // 96*256 = 24576 exact
    const int n = i >> 7, k = i & 127;
    const float w = (n < 64) ? Ws[k * 64 + n] : Wh[k * 128 + (n - 64)];
    WTb[i] = f2bu(w);

    for (int idx = i; idx < N_NODE; idx += 96 * 256) cnt[idx] = 0;
    if (i == 0) ovfn[0] = 0;

    if (blockIdx.x == 0) {
        __shared__ int bad;
        if (threadIdx.x == 0) bad = 0;
        __syncthreads();
        for (int t = threadIdx.x; t < 1000; t += 256) {
            const int w32 = edges[2 * t + 1];
            if (w32 != 0 && w32 != -1) bad = 1;
        }
        __syncthreads();
        if (threadIdx.x == 0) flag[0] = (bad == 0) ? 1 : 0;
    }
}

// ---------------------------------------------------------------------------
// MFMA node projection with SWAPPED operands (A = weights, B = hidden):
// D[row=outdim][col=node]; each lane holds 4 consecutive dims of ONE node
// -> one packed 8-B store per 16x16 tile.
// ---------------------------------------------------------------------------
__global__ __launch_bounds__(256) void node_tab_mfma(
    const float* __restrict__ hidden, const ushort_t* __restrict__ WTb,
    ushort_t* __restrict__ node_attn, ushort_t* __restrict__ node_msg)
{
    const int tid  = threadIdx.x;
    const int wid  = tid >> 6;
    const int lane = tid & 63;
    const int m16  = lane & 15;
    const int q    = lane >> 4;
    const int nb   = blockIdx.x * 64;
    const int row  = nb + wid * 16 + m16;               // this lane's node
    const int rowc = row < N_NODE ? row : N_NODE - 1;   // tail clamp

    v8s hfr[4];   // B-operand fragments: hidden[node=m16][k-chunk 8q+32c]
    #pragma unroll
    for (int c = 0; c < 4; ++c) {
        const float4 f0 = *(const float4*)(hidden + (size_t)rowc * 128 + 32 * c + 8 * q);
        const float4 f1 = *(const float4*)(hidden + (size_t)rowc * 128 + 32 * c + 8 * q + 4);
        v8s a;
        a[0] = (short)f2bu(f0.x); a[1] = (short)f2bu(f0.y);
        a[2] = (short)f2bu(f0.z); a[3] = (short)f2bu(f0.w);
        a[4] = (short)f2bu(f1.x); a[5] = (short)f2bu(f1.y);
        a[6] = (short)f2bu(f1.z); a[7] = (short)f2bu(f1.w);
        hfr[c] = a;
    }

    #pragma unroll
    for (int t = 0; t < 12; ++t) {
        v4f acc = {0.f, 0.f, 0.f, 0.f};
        #pragma unroll
        for (int c = 0; c < 4; ++c) {
            const v8s wfr = *(const v8s*)(WTb + (size_t)(16 * t + m16) * 128 + 32 * c + 8 * q);
            acc = __builtin_amdgcn_mfma_f32_16x16x32_bf16(wfr, hfr[c], acc, 0, 0, 0);
        }
        if (row < N_NODE) {
            const uint_t u0 = (uint_t)f2bu(acc[0]) | ((uint_t)f2bu(acc[1]) << 16);
            const uint_t u1 = (uint_t)f2bu(acc[2]) | ((uint_t)f2bu(acc[3]) << 16);
            const int dim = 16 * t + 4 * q;
            if (dim < 64) {
                uint2* dst = (uint2*)(node_attn + (size_t)row * 64 + dim);
                *dst = make_uint2(u0, u1);
            } else {
                uint2* dst = (uint2*)(node_msg + (size_t)row * 128 + (dim - 64));
                *dst = make_uint2(u0, u1);
            }
        }
    }
}

// ---------------------------------------------------------------------------
// Fused small tables: rel (401 blocks) | dt (731 blocks) | qr (64 blocks)
// ---------------------------------------------------------------------------
__global__ __launch_bounds__(128) void tables_kernel(
    const float* __restrict__ rela, const float* __restrict__ Wr,
    const float* __restrict__ Wtau, const float* __restrict__ Wh,
    const float* __restrict__ wt1, const float* __restrict__ bt1,
    const float* __restrict__ wt2, const float* __restrict__ bt2,
    const int* __restrict__ q_rel, const float* __restrict__ WqrW,
    const float* __restrict__ Wqrb, const int* __restrict__ flag,
    ushort_t* __restrict__ rel_attn, ushort_t* __restrict__ rel_msg,
    ushort_t* __restrict__ dt_attn,  ushort_t* __restrict__ dt_msg,
    ushort_t* __restrict__ Xqr)
{
    const int b = blockIdx.x, tid = threadIdx.x;
    __shared__ float h[IN_DIM];

    if (b < N_RELV) {
        const int r = b;
        h[tid] = rela[(size_t)r * IN_DIM + tid];
        __syncthreads();
        if (tid < ATTN_DIM) {
            float a = 0.f;
            #pragma unroll 8
            for (int d = 0; d < IN_DIM; ++d) a += h[d] * Wr[d * ATTN_DIM + tid];
            rel_attn[(size_t)r * ATTN_DIM + tid] = f2bu(a);
        }
        float m = 0.f;
        #pragma unroll 8
        for (int d = 0; d < IN_DIM; ++d) m += h[d] * Wh[d * OUT_DIM + tid];
        rel_msg[(size_t)r * OUT_DIM + tid] = f2bu(m);
    } else if (b < N_RELV + N_DT) {
        const int i = b - N_RELV;
        const float dt = (float)(i - 365);
        h[tid] = wt1[tid] * dt + bt1[tid] + sinf(wt2[tid] * dt + bt2[tid]);
        __syncthreads();
        if (tid < ATTN_DIM) {
            float a = 0.f;
            #pragma unroll 8
            for (int d = 0; d < IN_DIM; ++d) a += h[d] * Wtau[d * ATTN_DIM + tid];
            dt_attn[(size_t)i * ATTN_DIM + tid] = f2bu(a);
        }
        float m = 0.f;
        #pragma unroll 8
        for (int d = 0; d < IN_DIM; ++d) m += h[d] * Wh[d * OUT_DIM + tid];
        dt_msg[(size_t)i * OUT_DIM + tid] = f2bu(m);
    } else {
        const int qn  = b - N_RELV - N_DT;
        const int i64 = flag[0];
        const int rel = clampi(q_rel[i64 ? 2 * qn : qn], 0, N_RELV - 1);
        h[tid] = rela[(size_t)rel * IN_DIM + tid];
        __syncthreads();
        if (tid < ATTN_DIM) {
            float acc = Wqrb[tid];
            #pragma unroll 8
            for (int d = 0; d < IN_DIM; ++d) acc += h[d] * WqrW[d * ATTN_DIM + tid];
            Xqr[(size_t)qn * ATTN_DIM + tid] = f2bu(acc);
        }
    }
}

// relu-dot over this lane's 8 dims for one edge
__device__ __forceinline__ float dot8(uint4 xs, uint4 xr, uint4 xt, uint4 xq,
                                      float4 wA, float4 wB)
{
    float s0, s1, v;
    s0 = blo(xs.x) + blo(xr.x) + blo(xt.x) + blo(xq.x);
    s1 = bhi(xs.x) + bhi(xr.x) + bhi(xt.x) + bhi(xq.x);
    v  = fmaxf(s0, 0.f) * wA.x + fmaxf(s1, 0.f) * wA.y;
    s0 = blo(xs.y) + blo(xr.y) + blo(xt.y) + blo(xq.y);
    s1 = bhi(xs.y) + bhi(xr.y) + bhi(xt.y) + bhi(xq.y);
    v += fmaxf(s0, 0.f) * wA.z + fmaxf(s1, 0.f) * wA.w;
    s0 = blo(xs.z) + blo(xr.z) + blo(xt.z) + blo(xq.z);
    s1 = bhi(xs.z) + bhi(xr.z) + bhi(xt.z) + bhi(xq.z);
    v += fmaxf(s0, 0.f) * wB.x + fmaxf(s1, 0.f) * wB.y;
    s0 = blo(xs.w) + blo(xr.w) + blo(xt.w) + blo(xq.w);
    s1 = bhi(xs.w) + bhi(xr.w) + bhi(xt.w) + bhi(xq.w);
    v += fmaxf(s0, 0.f) * wB.z + fmaxf(s1, 0.f) * wB.w;
    return v;
}

// ---------------------------------------------------------------------------
// Phase 1: per-edge alpha. 8 lanes per edge, 2 edges per group (16/wave).
// meta entry = int2: x = sub | di<<17 | (rel&31)<<27 ; y = rel>>5 | fp16(alpha)<<16
// ---------------------------------------------------------------------------
__global__ __launch_bounds__(256) void alpha_scatter(
    const int* __restrict__ edges, const int* __restrict__ q_tau,
    const ushort_t* __restrict__ node_attn, const ushort_t* __restrict__ rel_attn,
    const ushort_t* __restrict__ dt_attn,  const ushort_t* __restrict__ Xqr,
    const float* __restrict__ w_alpha_W, const float* __restrict__ w_alpha_b,
    const int* __restrict__ flag, int* __restrict__ cnt,
    int2* __restrict__ meta, int* __restrict__ ovfn, int4* __restrict__ ovfl)
{
    const int g   = threadIdx.x & 7;
    const int grp = threadIdx.x >> 3;               // 0..31
    const int e0  = blockIdx.x * 64 + grp * 2;
    const int i64 = flag[0];

    const float4 wA = *(const float4*)(w_alpha_W + 8 * g);
    const float4 wB = *(const float4*)(w_alpha_W + 8 * g + 4);

    const int ea = e0     < N_EDGE ? e0     : N_EDGE - 1;
    const int eb = e0 + 1 < N_EDGE ? e0 + 1 : N_EDGE - 1;

    int r0, rel0, tau0, sub0, obj0, r1, rel1, tau1, sub1, obj1;
    parse_edge(edges, ea, i64, r0, rel0, tau0, sub0, obj0);
    parse_edge(edges, eb, i64, r1, rel1, tau1, sub1, obj1);
    const int tq0 = q_tau[i64 ? 2 * r0 : r0];
    const int tq1 = q_tau[i64 ? 2 * r1 : r1];
    if (tau0 < 0) tau0 = tq0;
    if (tau1 < 0) tau1 = tq1;
    const int di0 = clampi(tau0 - tq0 + 365, 0, N_DT - 1);
    const int di1 = clampi(tau1 - tq1 + 365, 0, N_DT - 1);

    // issue all 8 gathers back-to-back (max MLP)
    const uint4 xs0 = *(const uint4*)(node_attn + (size_t)sub0 * ATTN_DIM + 8 * g);
    const uint4 xr0 = *(const uint4*)(rel_attn + (size_t)rel0 * ATTN_DIM + 8 * g);
    const uint4 xt0 = *(const uint4*)(dt_attn  + (size_t)di0  * ATTN_DIM + 8 * g);
    const uint4 xq0 = *(const uint4*)(Xqr      + (size_t)r0   * ATTN_DIM + 8 * g);
    const uint4 xs1 = *(const uint4*)(node_attn + (size_t)sub1 * ATTN_DIM + 8 * g);
    const uint4 xr1 = *(const uint4*)(rel_attn + (size_t)rel1 * ATTN_DIM + 8 * g);
    const uint4 xt1 = *(const uint4*)(dt_attn  + (size_t)di1  * ATTN_DIM + 8 * g);
    const uint4 xq1 = *(const uint4*)(Xqr      + (size_t)r1   * ATTN_DIM + 8 * g);

    float v0 = dot8(xs0, xr0, xt0, xq0, wA, wB);
    float v1 = dot8(xs1, xr1, xt1, xq1, wA, wB);
    v0 += __shfl_down(v0, 4, 8);
    v1 += __shfl_down(v1, 4, 8);
    v0 += __shfl_down(v0, 2, 8);
    v1 += __shfl_down(v1, 2, 8);
    v0 += __shfl_down(v0, 1, 8);
    v1 += __shfl_down(v1, 1, 8);

    if (g == 0) {
        const float wb = w_alpha_b[0];
        if (e0 < N_EDGE) {
            const float alpha = 1.f / (1.f + __expf(-(v0 + wb)));
            const int pos = atomicAdd(&cnt[obj0], 1);
            if (pos < CAP) {
                const uint_t px = (uint_t)sub0 | ((uint_t)di0 << 17) | ((uint_t)(rel0 & 31) << 27);
                const uint_t py = (uint_t)(rel0 >> 5) |
                                  ((uint_t)__half_as_ushort(__float2half_rn(alpha)) << 16);
                meta[(size_t)obj0 * CAP + pos] = make_int2((int)px, (int)py);
            } else {
                const int ov = atomicAdd(ovfn, 1);
                if (ov < N_EDGE)
                    ovfl[ov] = make_int4(sub0 | (di0 << 17), rel0 | (obj0 << 9),
                                         __float_as_int(alpha), 0);
            }
        }
        if (e0 + 1 < N_EDGE) {
            const float alpha = 1.f / (1.f + __expf(-(v1 + wb)));
            const int pos = atomicAdd(&cnt[obj1], 1);
            if (pos < CAP) {
                const uint_t px = (uint_t)sub1 | ((uint_t)di1 << 17) | ((uint_t)(rel1 & 31) << 27);
                const uint_t py = (uint_t)(rel1 >> 5) |
                                  ((uint_t)__half_as_ushort(__float2half_rn(alpha)) << 16);
                meta[(size_t)obj1 * CAP + pos] = make_int2((int)px, (int)py);
            } else {
                const int ov = atomicAdd(ovfn, 1);
                if (ov < N_EDGE)
                    ovfl[ov] = make_int4(sub1 | (di1 << 17), rel1 | (obj1 << 9),
                                         __float_as_int(alpha), 0);
            }
        }
    }
}

// ---------------------------------------------------------------------------
// Phase 2: per-node aggregation from padded buckets, no atomics, unroll 4.
// ---------------------------------------------------------------------------
__device__ __forceinline__ void meta_decode(int2 m, int& sub, int& di, int& rel,
                                            float& al)
{
    sub = m.x & 0x1FFFF;
    di  = ((uint_t)m.x >> 17) & 0x3FF;
    rel = (((uint_t)m.x >> 27) & 31) | (((uint_t)m.y & 0xF) << 5);
    al  = __half2float(__ushort_as_half((ushort_t)((uint_t)m.y >> 16)));
}

__global__ __launch_bounds__(256) void agg_kernel(
    const int* __restrict__ cnt, const int2* __restrict__ meta,
    const int* __restrict__ ovfn, const int4* __restrict__ ovfl,
    const ushort_t* __restrict__ node_msg, const ushort_t* __restrict__ rel_msg,
    const ushort_t* __restrict__ dt_msg, float* __restrict__ out)
{
    const int lane = threadIdx.x & 63;
    const int n    = blockIdx.x * 4 + (threadIdx.x >> 6);

    int m = cnt[n]; if (m > CAP) m = CAP;
    const int2* row = meta + (size_t)n * CAP;
    float a0 = 0.f, a1 = 0.f;
    int j = 0;
    for (; j + 3 < m; j += 4) {
        const int2 m0 = row[j], m1 = row[j + 1], m2 = row[j + 2], m3 = row[j + 3];
        int s0, d0, r0; float w0; meta_decode(m0, s0, d0, r0, w0);
        int s1, d1, r1; float w1; meta_decode(m1, s1, d1, r1, w1);
        int s2, d2, r2; float w2; meta_decode(m2, s2, d2, r2, w2);
        int s3, d3, r3; float w3; meta_decode(m3, s3, d3, r3, w3);
        const uint_t am0 = *(const uint_t*)(node_msg + (size_t)s0 * 128 + 2 * lane);
        const uint_t bm0 = *(const uint_t*)(rel_msg  + (size_t)r0 * 128 + 2 * lane);
        const uint_t tm0 = *(const uint_t*)(dt_msg   + (size_t)d0 * 128 + 2 * lane);
        const uint_t am1 = *(const uint_t*)(node_msg + (size_t)s1 * 128 + 2 * lane);
        const uint_t bm1 = *(const uint_t*)(rel_msg  + (size_t)r1 * 128 + 2 * lane);
        const uint_t tm1 = *(const uint_t*)(dt_msg   + (size_t)d1 * 128 + 2 * lane);
        const uint_t am2 = *(const uint_t*)(node_msg + (size_t)s2 * 128 + 2 * lane);
        const uint_t bm2 = *(const uint_t*)(rel_msg  + (size_t)r2 * 128 + 2 * lane);
        const uint_t tm2 = *(const uint_t*)(dt_msg   + (size_t)d2 * 128 + 2 * lane);
        const uint_t am3 = *(const uint_t*)(node_msg + (size_t)s3 * 128 + 2 * lane);
        const uint_t bm3 = *(const uint_t*)(rel_msg  + (size_t)r3 * 128 + 2 * lane);
        const uint_t tm3 = *(const uint_t*)(dt_msg   + (size_t)d3 * 128 + 2 * lane);
        a0 += w0 * (blo(am0) + blo(bm0) + blo(tm0));
        a1 += w0 * (bhi(am0) + bhi(bm0) + bhi(tm0));
        a0 += w1 * (blo(am1) + blo(bm1) + blo(tm1));
        a1 += w1 * (bhi(am1) + bhi(bm1) + bhi(tm1));
        a0 += w2 * (blo(am2) + blo(bm2) + blo(tm2));
        a1 += w2 * (bhi(am2) + bhi(bm2) + bhi(tm2));
        a0 += w3 * (blo(am3) + blo(bm3) + blo(tm3));
        a1 += w3 * (bhi(am3) + bhi(bm3) + bhi(tm3));
    }
    for (; j < m; ++j) {
        const int2 m0 = row[j];
        int s0, d0, r0; float w0; meta_decode(m0, s0, d0, r0, w0);
        const uint_t am0 = *(const uint_t*)(node_msg + (size_t)s0 * 128 + 2 * lane);
        const uint_t bm0 = *(const uint_t*)(rel_msg  + (size_t)r0 * 128 + 2 * lane);
        const uint_t tm0 = *(const uint_t*)(dt_msg   + (size_t)d0 * 128 + 2 * lane);
        a0 += w0 * (blo(am0) + blo(bm0) + blo(tm0));
        a1 += w0 * (bhi(am0) + bhi(bm0) + bhi(tm0));
    }

    // overflow entries (normally none): scan and filter by obj == n
    int nov = ovfn[0]; if (nov > N_EDGE) nov = N_EDGE;
    for (int i = 0; i < nov; ++i) {
        const int4 mo = ovfl[i];
        const int objo = (int)((uint_t)mo.y >> 9);
        if (objo != n) continue;
        const int subo = mo.x & 0x1FFFF;
        const int dio  = (int)((uint_t)mo.x >> 17);
        const int relo = mo.y & 0x1FF;
        const float alo = __int_as_float(mo.z);
        const uint_t am = *(const uint_t*)(node_msg + (size_t)subo * 128 + 2 * lane);
        const uint_t bm = *(const uint_t*)(rel_msg  + (size_t)relo * 128 + 2 * lane);
        const uint_t tm = *(const uint_t*)(dt_msg   + (size_t)dio  * 128 + 2 * lane);
        a0 += alo * (blo(am) + blo(bm) + blo(tm));
        a1 += alo * (bhi(am) + bhi(bm) + bhi(tm));
    }

    ((float2*)(out + (size_t)n * OUT_DIM))[lane] = make_float2(a0, a1);
}

// ---------------------------------------------------------------------------
// Fallback: single-pass atomic edge kernel (small-workspace path).
// ---------------------------------------------------------------------------
__global__ __launch_bounds__(256) void edge_atomic_kernel(
    const int* __restrict__ edges, const int* __restrict__ q_tau,
    const ushort_t* __restrict__ node_attn, const ushort_t* __restrict__ node_msg,
    const ushort_t* __restrict__ rel_attn,  const ushort_t* __restrict__ rel_msg,
    const ushort_t* __restrict__ dt_attn,   const ushort_t* __restrict__ dt_msg,
    const ushort_t* __restrict__ Xqr,
    const float* __restrict__ w_alpha_W, const float* __restrict__ w_alpha_b,
    const int* __restrict__ flag, float* __restrict__ out)
{
    const int lane = threadIdx.x & 63;
    const int e    = blockIdx.x * 4 + (threadIdx.x >> 6);
    const int i64  = flag[0];

    int r, rel, tau, sub, obj;
    parse_edge(edges, e, i64, r, rel, tau, sub, obj);
    const int tq = q_tau[i64 ? 2 * r : r];
    if (tau < 0) tau = tq;
    const int di = clampi(tau - tq + 365, 0, N_DT - 1);

    const float xs = bu2f(node_attn[(size_t)sub * ATTN_DIM + lane]);
    const float xr = bu2f(rel_attn[(size_t)rel * ATTN_DIM + lane]);
    const float xt = bu2f(dt_attn[(size_t)di  * ATTN_DIM + lane]);
    const float xq = bu2f(Xqr[(size_t)r * ATTN_DIM + lane]);

    float v = fmaxf(xs + xr + xq + xt, 0.f) * w_alpha_W[lane];
    #pragma unroll
    for (int off = 32; off > 0; off >>= 1)
        v += __shfl_down(v, off, 64);
    v = __shfl(v, 0, 64);
    const float alpha = 1.f / (1.f + __expf(-(v + w_alpha_b[0])));

    const uint_t am = *(const uint_t*)(node_msg + (size_t)sub * 128 + 2 * lane);
    const uint_t bm = *(const uint_t*)(rel_msg  + (size_t)rel * 128 + 2 * lane);
    const uint_t tm = *(const uint_t*)(dt_msg   + (size_t)di  * 128 + 2 * lane);
    const float mx = blo(am) + blo(bm) + blo(tm);
    const float my = bhi(am) + bhi(bm) + bhi(tm);

    float* dst = out + (size_t)obj * OUT_DIM;
    atomicAdd(dst + 2 * lane,     alpha * mx);
    atomicAdd(dst + 2 * lane + 1, alpha * my);
}

// ===========================================================================
extern "C" void kernel_launch(void* const* d_in, const int* in_sizes, int n_in,
                              void* d_out, int out_size, void* d_ws, size_t ws_size,
                              hipStream_t stream)
{
    const int*   q_rel  = (const int*)d_in[1];
    const int*   q_tau  = (const int*)d_in[2];
    const float* hidden = (const float*)d_in[3];
    const int*   edges  = (const int*)d_in[4];
    const float* rela   = (const float*)d_in[7];
    const float* Ws     = (const float*)d_in[8];
    const float* Wr     = (const float*)d_in[9];
    const float* WqrW   = (const float*)d_in[10];
    const float* Wqrb   = (const float*)d_in[11];
    const float* Wtau   = (const float*)d_in[12];
    const float* waW    = (const float*)d_in[13];
    const float* wab    = (const float*)d_in[14];
    const float* Wh     = (const float*)d_in[15];
    const float* wt1    = (const float*)d_in[16];
    const float* bt1    = (const float*)d_in[17];
    const float* wt2    = (const float*)d_in[18];
    const float* bt2    = (const float*)d_in[19];
    float* out = (float*)d_out;

    // --- workspace carve (256-B aligned chunks) ---
    char* p = (char*)d_ws;
    size_t off = 0;
    auto carve = [&](size_t bytes) {
        char* q = p + off;
        off = (off + bytes + 255) & ~(size_t)255;
        return q;
    };
    int*      flag      = (int*)     carve(64);
    int*      cnt       = (int*)     carve((size_t)N_NODE * 4);
    int*      ovfn      = (int*)     carve(64);
    ushort_t* WTb       = (ushort_t*)carve((size_t)192 * 128 * 2);
    ushort_t* XqrB      = (ushort_t*)carve((size_t)N_QUERY * ATTN_DIM * 2);
    ushort_t* rel_attn  = (ushort_t*)carve((size_t)N_RELV * ATTN_DIM * 2);
    ushort_t* rel_msg   = (ushort_t*)carve((size_t)N_RELV * OUT_DIM * 2);
    ushort_t* dt_attn   = (ushort_t*)carve((size_t)N_DT * ATTN_DIM * 2);
    ushort_t* dt_msg    = (ushort_t*)carve((size_t)N_DT * OUT_DIM * 2);
    ushort_t* node_attn = (ushort_t*)carve((size_t)N_NODE * ATTN_DIM * 2);
    ushort_t* node_msg  = (ushort_t*)carve((size_t)N_NODE * OUT_DIM * 2);
    int2*     meta      = (int2*)    carve((size_t)N_NODE * CAP * 8);
    int4*     ovfl      = (int4*)    carve((size_t)N_EDGE * 16);
    const size_t need_full = off;

    // shared precompute (both paths)
    prep_kernel<<<96, 256, 0, stream>>>(edges, Ws, Wh, WTb, flag, cnt, ovfn);
    tables_kernel<<<N_RELV + N_DT + N_QUERY, 128, 0, stream>>>(
        rela, Wr, Wtau, Wh, wt1, bt1, wt2, bt2, q_rel, WqrW, Wqrb, flag,
        rel_attn, rel_msg, dt_attn, dt_msg, XqrB);
    node_tab_mfma<<<(N_NODE + 63) / 64, 256, 0, stream>>>(hidden, WTb,
                                                          node_attn, node_msg);

    if (ws_size >= need_full) {
        alpha_scatter<<<(N_EDGE + 63) / 64, 256, 0, stream>>>(
            edges, q_tau, node_attn, rel_attn, dt_attn, XqrB,
            waW, wab, flag, cnt, meta, ovfn, ovfl);
        agg_kernel<<<N_NODE / 4, 256, 0, stream>>>(cnt, meta, ovfn, ovfl,
                                                   node_msg, rel_msg, dt_msg, out);
    } else {
        (void)hipMemsetAsync(out, 0, (size_t)out_size * sizeof(float), stream);
        edge_atomic_kernel<<<N_EDGE / 4, 256, 0, stream>>>(edges, q_tau,
                                                           node_attn, node_msg,
                                                           rel_attn, rel_msg,
                                                           dt_attn, dt_msg, XqrB,
                                                           waW, wab, flag, out);
    }
}

// Round 3
// 200.167 us; speedup vs baseline: 1.4420x; 1.0848x over previous
//
#include <hip/hip_runtime.h>
#include <hip/hip_fp16.h>

#define IN_DIM   128
#define OUT_DIM  128
#define ATTN_DIM 64
#define N_RELV   401
#define N_NODE   50000
#define N_EDGE   500000
#define N_QUERY  64
#define N_DT     731
#define CAP      40       // padded bucket capacity (deg ~ Poisson(10); P(>=40) ~ 1e-11)

#define NB_NODE  782      // ceil(50000/64)
#define NB_RELDT 566      // ceil((401+731)/2)
#define NB_QR    32       // 64 queries, 2/block
#define NB_TOT   (NB_NODE + NB_RELDT + NB_QR + 1)

typedef unsigned short ushort_t;
typedef unsigned int   uint_t;
typedef __attribute__((ext_vector_type(8))) short v8s;   // 8 bf16 (4 VGPRs)
typedef __attribute__((ext_vector_type(4))) float v4f;

__device__ __forceinline__ int clampi(int v, int lo, int hi) {
    return v < lo ? lo : (v > hi ? hi : v);
}
__device__ __forceinline__ float bu2f(ushort_t u) {
    union { uint_t i; float f; } v; v.i = ((uint_t)u) << 16; return v.f;
}
__device__ __forceinline__ float blo(uint_t u) { return bu2f((ushort_t)(u & 0xffff)); }
__device__ __forceinline__ float bhi(uint_t u) { return bu2f((ushort_t)(u >> 16)); }
__device__ __forceinline__ ushort_t f2bu(float f) {   // RNE, finite inputs
    union { float f; uint_t i; } v; v.f = f;
    const uint_t x = v.i;
    return (ushort_t)((x + 0x7fffu + ((x >> 16) & 1u)) >> 16);
}
// packed RNE f32x2 -> bf16x2 (low = a, high = b)
__device__ __forceinline__ uint_t cvtpk(float a, float b) {
    uint_t r;
    asm("v_cvt_pk_bf16_f32 %0, %1, %2" : "=v"(r) : "v"(a), "v"(b));
    return r;
}

// edge parse (int32 vs int64 rows)
__device__ __forceinline__ void parse_edge(const int* __restrict__ edges, int e,
                                           int i64, int& r, int& rel, int& tau,
                                           int& sub, int& obj) {
    if (i64) {
        const int* E = edges + (size_t)e * 14;
        r = E[0]; rel = E[4]; tau = E[8]; sub = E[10]; obj = E[12];
    } else {
        const int* E = edges + (size_t)e * 7;
        r = E[0]; rel = E[2]; tau = E[4]; sub = E[5]; obj = E[6];
    }
    r   = clampi(r,   0, N_QUERY - 1);
    rel = clampi(rel, 0, N_RELV - 1);
    sub = clampi(sub, 0, N_NODE - 1);
    obj = clampi(obj, 0, N_NODE - 1);
}

// LDS weight-table swizzle: logical (row, byte-in-row) -> banked offset.
// XOR bits 4..6 with row&7: ds_read_b128 per fragment becomes 2-way (free).
__device__ __forceinline__ int swz_byte(int row, int byte_in_row) {
    return (row * 256 + byte_in_row) ^ ((row & 7) << 4);
}

// ---------------------------------------------------------------------------
// fused_pre: one kernel, four block roles.
//  [0, NB_NODE)            : MFMA node projection, weights staged in LDS
//  [NB_NODE, +NB_RELDT)    : rel/dt tables (2 rows per block) + cnt zeroing
//  [.., +NB_QR)            : Xqr (2 queries per block, self-detected i64)
//  last                    : global i64 flag + ovfn zero
// ---------------------------------------------------------------------------
__global__ __launch_bounds__(256) void fused_pre(
    const float* __restrict__ hidden, const float* __restrict__ Ws,
    const float* __restrict__ Wh,   const float* __restrict__ rela,
    const float* __restrict__ Wr,   const float* __restrict__ Wtau,
    const float* __restrict__ wt1,  const float* __restrict__ bt1,
    const float* __restrict__ wt2,  const float* __restrict__ bt2,
    const int* __restrict__ q_rel,  const float* __restrict__ WqrW,
    const float* __restrict__ Wqrb, const int* __restrict__ edges,
    ushort_t* __restrict__ node_attn, ushort_t* __restrict__ node_msg,
    ushort_t* __restrict__ rel_attn,  ushort_t* __restrict__ rel_msg,
    ushort_t* __restrict__ dt_attn,   ushort_t* __restrict__ dt_msg,
    ushort_t* __restrict__ Xqr,
    int* __restrict__ flag, int* __restrict__ cnt, int* __restrict__ ovfn)
{
    __shared__ ushort_t shw[192 * 128];          // 48 KiB
    const int bid = blockIdx.x, tid = threadIdx.x;

    if (bid < NB_NODE) {
        // ---- stage [Ws | Wh] transposed + bf16 into swizzled LDS ----
        // WTb[row][col] = row<64 ? Ws[col][row] : Wh[col][row-64]
        #pragma unroll
        for (int i = 0; i < 4; ++i) {            // Ws: 1024 col-pair quads
            const int pi = tid + 256 * i;
            const int kp = pi >> 4;              // col pair 0..63
            const int n4 = (pi & 15) * 4;        // row group
            const float4 A = *(const float4*)(Ws + (size_t)(2 * kp) * 64 + n4);
            const float4 B = *(const float4*)(Ws + (size_t)(2 * kp + 1) * 64 + n4);
            const float Aa[4] = {A.x, A.y, A.z, A.w};
            const float Bа[4] = {B.x, B.y, B.z, B.w};
            #pragma unroll
            for (int j = 0; j < 4; ++j) {
                const int row = n4 + j;
                const uint_t u = (uint_t)f2bu(Aa[j]) | ((uint_t)f2bu(Bа[j]) << 16);
                *(uint_t*)((char*)shw + swz_byte(row, kp * 4)) = u;
            }
        }
        #pragma unroll
        for (int i = 0; i < 8; ++i) {            // Wh: 2048 col-pair quads
            const int pi = tid + 256 * i;
            const int kp = pi >> 5;              // col pair 0..63
            const int n4 = (pi & 31) * 4;        // row group 0..124
            const float4 A = *(const float4*)(Wh + (size_t)(2 * kp) * 128 + n4);
            const float4 B = *(const float4*)(Wh + (size_t)(2 * kp + 1) * 128 + n4);
            const float Aa[4] = {A.x, A.y, A.z, A.w};
            const float Bа[4] = {B.x, B.y, B.z, B.w};
            #pragma unroll
            for (int j = 0; j < 4; ++j) {
                const int row = 64 + n4 + j;
                const uint_t u = (uint_t)f2bu(Aa[j]) | ((uint_t)f2bu(Bа[j]) << 16);
                *(uint_t*)((char*)shw + swz_byte(row, kp * 4)) = u;
            }
        }
        __syncthreads();

        const int wid  = tid >> 6;
        const int lane = tid & 63;
        const int m16  = lane & 15;
        const int q    = lane >> 4;
        const int nb   = bid * 64;
        const int row  = nb + wid * 16 + m16;               // this lane's node
        const int rowc = row < N_NODE ? row : N_NODE - 1;   // tail clamp

        v8s hfr[4];   // B fragments: hidden[node=m16 row][k chunk]
        #pragma unroll
        for (int c = 0; c < 4; ++c) {
            const float4 f0 = *(const float4*)(hidden + (size_t)rowc * 128 + 32 * c + 8 * q);
            const float4 f1 = *(const float4*)(hidden + (size_t)rowc * 128 + 32 * c + 8 * q + 4);
            union { v8s s; uint4 u; } uu;
            uu.u = make_uint4(cvtpk(f0.x, f0.y), cvtpk(f0.z, f0.w),
                              cvtpk(f1.x, f1.y), cvtpk(f1.z, f1.w));
            hfr[c] = uu.s;
        }

        #pragma unroll
        for (int t = 0; t < 12; ++t) {
            v4f acc = {0.f, 0.f, 0.f, 0.f};
            #pragma unroll
            for (int c = 0; c < 4; ++c) {
                const v8s wfr = *(const v8s*)((const char*)shw +
                                  swz_byte(16 * t + m16, (32 * c + 8 * q) * 2));
                acc = __builtin_amdgcn_mfma_f32_16x16x32_bf16(wfr, hfr[c], acc, 0, 0, 0);
            }
            if (row < N_NODE) {
                const uint_t u0 = cvtpk(acc[0], acc[1]);
                const uint_t u1 = cvtpk(acc[2], acc[3]);
                const int dim = 16 * t + 4 * q;
                if (dim < 64) {
                    *(uint2*)(node_attn + (size_t)row * 64 + dim) = make_uint2(u0, u1);
                } else {
                    *(uint2*)(node_msg + (size_t)row * 128 + (dim - 64)) = make_uint2(u0, u1);
                }
            }
        }
    } else if (bid < NB_NODE + NB_RELDT) {
        const int bid2   = bid - NB_NODE;
        const int half   = tid >> 7;             // 0/1: row within block
        const int t128   = tid & 127;
        const int rowid  = bid2 * 2 + half;      // 0..1131
        float* h = (float*)shw + half * 128;

        if (rowid < N_RELV) {
            h[t128] = rela[(size_t)rowid * IN_DIM + t128];
        } else {
            const float dtv = (float)((rowid - N_RELV) - 365);
            h[t128] = wt1[t128] * dtv + bt1[t128] + sinf(wt2[t128] * dtv + bt2[t128]);
        }
        __syncthreads();

        if (rowid < N_RELV) {
            if (t128 < ATTN_DIM) {
                float a = 0.f;
                #pragma unroll 8
                for (int d = 0; d < IN_DIM; ++d) a += h[d] * Wr[d * ATTN_DIM + t128];
                rel_attn[(size_t)rowid * ATTN_DIM + t128] = f2bu(a);
            }
            float m = 0.f;
            #pragma unroll 8
            for (int d = 0; d < IN_DIM; ++d) m += h[d] * Wh[d * OUT_DIM + t128];
            rel_msg[(size_t)rowid * OUT_DIM + t128] = f2bu(m);
        } else {
            const int i = rowid - N_RELV;
            if (t128 < ATTN_DIM) {
                float a = 0.f;
                #pragma unroll 8
                for (int d = 0; d < IN_DIM; ++d) a += h[d] * Wtau[d * ATTN_DIM + t128];
                dt_attn[(size_t)i * ATTN_DIM + t128] = f2bu(a);
            }
            float m = 0.f;
            #pragma unroll 8
            for (int d = 0; d < IN_DIM; ++d) m += h[d] * Wh[d * OUT_DIM + t128];
            dt_msg[(size_t)i * OUT_DIM + t128] = f2bu(m);
        }
        // cnt zeroing strip (566 blocks x 89 >= 50000)
        const int z = bid2 * 89 + tid;
        if (tid < 89 && z < N_NODE) cnt[z] = 0;
    } else if (bid < NB_NODE + NB_RELDT + NB_QR) {
        const int bid3 = bid - NB_NODE - NB_RELDT;
        const int half = tid >> 7;
        const int t128 = tid & 127;
        float* h  = (float*)shw + half * 128;
        int*   ok = (int*)((float*)shw + 512);

        if (tid == 0) *ok = 1;
        __syncthreads();
        const int w = edges[2 * tid + 1];
        if (w != 0 && w != -1) *ok = 0;          // benign race (all write 0)
        __syncthreads();
        const int i64 = *ok;

        const int qn  = bid3 * 2 + half;
        const int rel = clampi(q_rel[i64 ? 2 * qn : qn], 0, N_RELV - 1);
        h[t128] = rela[(size_t)rel * IN_DIM + t128];
        __syncthreads();
        if (t128 < ATTN_DIM) {
            float acc = Wqrb[t128];
            #pragma unroll 8
            for (int d = 0; d < IN_DIM; ++d) acc += h[d] * WqrW[d * ATTN_DIM + t128];
            Xqr[(size_t)qn * ATTN_DIM + t128] = f2bu(acc);
        }
    } else {
        // global i64 flag (1000-sample detect) + ovfn zero
        int* ok = (int*)shw;
        if (tid == 0) *ok = 0;
        __syncthreads();
        int badv = 0;
        for (int t = tid; t < 1000; t += 256) {
            const int w = edges[2 * t + 1];
            if (w != 0 && w != -1) badv = 1;
        }
        if (badv) *ok = 1;
        __syncthreads();
        if (tid == 0) { flag[0] = (*ok == 0) ? 1 : 0; ovfn[0] = 0; }
    }
}

// relu-dot over this lane's 8 dims for one edge
__device__ __forceinline__ float dot8(uint4 xs, uint4 xr, uint4 xt, uint4 xq,
                                      float4 wA, float4 wB)
{
    float s0, s1, v;
    s0 = blo(xs.x) + blo(xr.x) + blo(xt.x) + blo(xq.x);
    s1 = bhi(xs.x) + bhi(xr.x) + bhi(xt.x) + bhi(xq.x);
    v  = fmaxf(s0, 0.f) * wA.x + fmaxf(s1, 0.f) * wA.y;
    s0 = blo(xs.y) + blo(xr.y) + blo(xt.y) + blo(xq.y);
    s1 = bhi(xs.y) + bhi(xr.y) + bhi(xt.y) + bhi(xq.y);
    v += fmaxf(s0, 0.f) * wA.z + fmaxf(s1, 0.f) * wA.w;
    s0 = blo(xs.z) + blo(xr.z) + blo(xt.z) + blo(xq.z);
    s1 = bhi(xs.z) + bhi(xr.z) + bhi(xt.z) + bhi(xq.z);
    v += fmaxf(s0, 0.f) * wB.x + fmaxf(s1, 0.f) * wB.y;
    s0 = blo(xs.w) + blo(xr.w) + blo(xt.w) + blo(xq.w);
    s1 = bhi(xs.w) + bhi(xr.w) + bhi(xt.w) + bhi(xq.w);
    v += fmaxf(s0, 0.f) * wB.z + fmaxf(s1, 0.f) * wB.w;
    return v;
}

// ---------------------------------------------------------------------------
// Phase 1: per-edge alpha. 8 lanes per edge, 4 edges per group (32/wave).
// meta is TRANSPOSED: meta[pos * N_NODE + obj] (int2) -> writes cluster into
// pos-stripes that stay L2-resident (write merging works).
// entry: x = sub | di<<17 | (rel&31)<<27 ; y = (rel>>5) | fp16(alpha)<<16
// ---------------------------------------------------------------------------
__global__ __launch_bounds__(256) void alpha_scatter(
    const int* __restrict__ edges, const int* __restrict__ q_tau,
    const ushort_t* __restrict__ node_attn, const ushort_t* __restrict__ rel_attn,
    const ushort_t* __restrict__ dt_attn,  const ushort_t* __restrict__ Xqr,
    const float* __restrict__ w_alpha_W, const float* __restrict__ w_alpha_b,
    const int* __restrict__ flag, int* __restrict__ cnt,
    int2* __restrict__ meta, int* __restrict__ ovfn, int4* __restrict__ ovfl)
{
    const int g   = threadIdx.x & 7;
    const int grp = threadIdx.x >> 3;               // 0..31
    const int e0  = blockIdx.x * 128 + grp * 4;
    const int i64 = flag[0];

    const float4 wA = *(const float4*)(w_alpha_W + 8 * g);
    const float4 wB = *(const float4*)(w_alpha_W + 8 * g + 4);

    const int ec0 = e0     < N_EDGE ? e0     : N_EDGE - 1;
    const int ec1 = e0 + 1 < N_EDGE ? e0 + 1 : N_EDGE - 1;
    const int ec2 = e0 + 2 < N_EDGE ? e0 + 2 : N_EDGE - 1;
    const int ec3 = e0 + 3 < N_EDGE ? e0 + 3 : N_EDGE - 1;

    int r0, rel0, tau0, sub0, obj0; parse_edge(edges, ec0, i64, r0, rel0, tau0, sub0, obj0);
    int r1, rel1, tau1, sub1, obj1; parse_edge(edges, ec1, i64, r1, rel1, tau1, sub1, obj1);
    int r2, rel2, tau2, sub2, obj2; parse_edge(edges, ec2, i64, r2, rel2, tau2, sub2, obj2);
    int r3, rel3, tau3, sub3, obj3; parse_edge(edges, ec3, i64, r3, rel3, tau3, sub3, obj3);
    const int tq0 = q_tau[i64 ? 2 * r0 : r0];
    const int tq1 = q_tau[i64 ? 2 * r1 : r1];
    const int tq2 = q_tau[i64 ? 2 * r2 : r2];
    const int tq3 = q_tau[i64 ? 2 * r3 : r3];
    if (tau0 < 0) tau0 = tq0;
    if (tau1 < 0) tau1 = tq1;
    if (tau2 < 0) tau2 = tq2;
    if (tau3 < 0) tau3 = tq3;
    const int di0 = clampi(tau0 - tq0 + 365, 0, N_DT - 1);
    const int di1 = clampi(tau1 - tq1 + 365, 0, N_DT - 1);
    const int di2 = clampi(tau2 - tq2 + 365, 0, N_DT - 1);
    const int di3 = clampi(tau3 - tq3 + 365, 0, N_DT - 1);

    // 16 independent gathers in flight
    const uint4 xs0 = *(const uint4*)(node_attn + (size_t)sub0 * ATTN_DIM + 8 * g);
    const uint4 xr0 = *(const uint4*)(rel_attn + (size_t)rel0 * ATTN_DIM + 8 * g);
    const uint4 xt0 = *(const uint4*)(dt_attn  + (size_t)di0  * ATTN_DIM + 8 * g);
    const uint4 xq0 = *(const uint4*)(Xqr      + (size_t)r0   * ATTN_DIM + 8 * g);
    const uint4 xs1 = *(const uint4*)(node_attn + (size_t)sub1 * ATTN_DIM + 8 * g);
    const uint4 xr1 = *(const uint4*)(rel_attn + (size_t)rel1 * ATTN_DIM + 8 * g);
    const uint4 xt1 = *(const uint4*)(dt_attn  + (size_t)di1  * ATTN_DIM + 8 * g);
    const uint4 xq1 = *(const uint4*)(Xqr      + (size_t)r1   * ATTN_DIM + 8 * g);
    const uint4 xs2 = *(const uint4*)(node_attn + (size_t)sub2 * ATTN_DIM + 8 * g);
    const uint4 xr2 = *(const uint4*)(rel_attn + (size_t)rel2 * ATTN_DIM + 8 * g);
    const uint4 xt2 = *(const uint4*)(dt_attn  + (size_t)di2  * ATTN_DIM + 8 * g);
    const uint4 xq2 = *(const uint4*)(Xqr      + (size_t)r2   * ATTN_DIM + 8 * g);
    const uint4 xs3 = *(const uint4*)(node_attn + (size_t)sub3 * ATTN_DIM + 8 * g);
    const uint4 xr3 = *(const uint4*)(rel_attn + (size_t)rel3 * ATTN_DIM + 8 * g);
    const uint4 xt3 = *(const uint4*)(dt_attn  + (size_t)di3  * ATTN_DIM + 8 * g);
    const uint4 xq3 = *(const uint4*)(Xqr      + (size_t)r3   * ATTN_DIM + 8 * g);

    float v0 = dot8(xs0, xr0, xt0, xq0, wA, wB);
    float v1 = dot8(xs1, xr1, xt1, xq1, wA, wB);
    float v2 = dot8(xs2, xr2, xt2, xq2, wA, wB);
    float v3 = dot8(xs3, xr3, xt3, xq3, wA, wB);

    // butterfly within the 8-lane group: all lanes end with the full sums
    #pragma unroll
    for (int off = 4; off > 0; off >>= 1) {
        v0 += __shfl_xor(v0, off, 8);
        v1 += __shfl_xor(v1, off, 8);
        v2 += __shfl_xor(v2, off, 8);
        v3 += __shfl_xor(v3, off, 8);
    }

    if (g < 4 && e0 + g < N_EDGE) {
        const float vg  = g == 0 ? v0 : (g == 1 ? v1 : (g == 2 ? v2 : v3));
        const int objg  = g == 0 ? obj0 : (g == 1 ? obj1 : (g == 2 ? obj2 : obj3));
        const int subg  = g == 0 ? sub0 : (g == 1 ? sub1 : (g == 2 ? sub2 : sub3));
        const int dig   = g == 0 ? di0  : (g == 1 ? di1  : (g == 2 ? di2  : di3));
        const int relg  = g == 0 ? rel0 : (g == 1 ? rel1 : (g == 2 ? rel2 : rel3));
        const float alpha = 1.f / (1.f + __expf(-(vg + w_alpha_b[0])));
        const int pos = atomicAdd(&cnt[objg], 1);
        if (pos < CAP) {
            const uint_t px = (uint_t)subg | ((uint_t)dig << 17) | ((uint_t)(relg & 31) << 27);
            const uint_t py = (uint_t)(relg >> 5) |
                              ((uint_t)__half_as_ushort(__float2half_rn(alpha)) << 16);
            meta[(size_t)pos * N_NODE + objg] = make_int2((int)px, (int)py);
        } else {
            const int ov = atomicAdd(ovfn, 1);
            if (ov < N_EDGE)
                ovfl[ov] = make_int4(subg | (dig << 17), relg | (objg << 9),
                                     __float_as_int(alpha), 0);
        }
    }
}

// ---------------------------------------------------------------------------
// Phase 2: per-node aggregation. Half-wave per edge (2 edges per step),
// uint2 (8B) gathers, unroll 2 steps, __shfl_xor(32) combine, float4 store.
// ---------------------------------------------------------------------------
__device__ __forceinline__ void agg_edge(
    int2 m, int l32,
    const ushort_t* __restrict__ node_msg, const ushort_t* __restrict__ rel_msg,
    const ushort_t* __restrict__ dt_msg,
    float& a0, float& a1, float& a2, float& a3)
{
    const int sub = m.x & 0x1FFFF;
    const int di  = ((uint_t)m.x >> 17) & 0x3FF;
    const int rel = (((uint_t)m.x >> 27) & 31) | (((uint_t)m.y & 0xF) << 5);
    const float al = __half2float(__ushort_as_half((ushort_t)((uint_t)m.y >> 16)));
    const uint2 am = *(const uint2*)(node_msg + (size_t)sub * 128 + 4 * l32);
    const uint2 bm = *(const uint2*)(rel_msg  + (size_t)rel * 128 + 4 * l32);
    const uint2 tm = *(const uint2*)(dt_msg   + (size_t)di  * 128 + 4 * l32);
    a0 += al * (blo(am.x) + blo(bm.x) + blo(tm.x));
    a1 += al * (bhi(am.x) + bhi(bm.x) + bhi(tm.x));
    a2 += al * (blo(am.y) + blo(bm.y) + blo(tm.y));
    a3 += al * (bhi(am.y) + bhi(bm.y) + bhi(tm.y));
}

__global__ __launch_bounds__(256) void agg_kernel(
    const int* __restrict__ cnt, const int2* __restrict__ meta,
    const int* __restrict__ ovfn, const int4* __restrict__ ovfl,
    const ushort_t* __restrict__ node_msg, const ushort_t* __restrict__ rel_msg,
    const ushort_t* __restrict__ dt_msg, float* __restrict__ out)
{
    const int lane = threadIdx.x & 63;
    const int half = lane >> 5;                  // 0/1: which edge of the pair
    const int l32  = lane & 31;                  // covers dims 4*l32..+3
    const int n    = blockIdx.x * 4 + (threadIdx.x >> 6);

    int m = cnt[n]; if (m > CAP) m = CAP;
    float a0 = 0.f, a1 = 0.f, a2 = 0.f, a3 = 0.f;

    int j = 0;
    for (; j + 3 < m; j += 4) {                  // 4 edges per iteration
        const int2 ma = meta[(size_t)(j + half) * N_NODE + n];
        const int2 mb = meta[(size_t)(j + 2 + half) * N_NODE + n];
        agg_edge(ma, l32, node_msg, rel_msg, dt_msg, a0, a1, a2, a3);
        agg_edge(mb, l32, node_msg, rel_msg, dt_msg, a0, a1, a2, a3);
    }
    for (; j + 1 < m; j += 2) {                  // 2 edges
        const int2 ma = meta[(size_t)(j + half) * N_NODE + n];
        agg_edge(ma, l32, node_msg, rel_msg, dt_msg, a0, a1, a2, a3);
    }
    if (j < m && half == 0) {                    // odd tail: half 0 only
        const int2 ma = meta[(size_t)j * N_NODE + n];
        agg_edge(ma, l32, node_msg, rel_msg, dt_msg, a0, a1, a2, a3);
    }

    // overflow entries (normally none): scan, filter by obj == n, half 0 only
    int nov = ovfn[0]; if (nov > N_EDGE) nov = N_EDGE;
    for (int i = 0; i < nov; ++i) {
        const int4 mo = ovfl[i];
        const int objo = (int)((uint_t)mo.y >> 9);
        if (objo != n || half != 0) continue;
        const int subo = mo.x & 0x1FFFF;
        const int dio  = (int)((uint_t)mo.x >> 17);
        const int relo = mo.y & 0x1FF;
        const float alo = __int_as_float(mo.z);
        const uint2 am = *(const uint2*)(node_msg + (size_t)subo * 128 + 4 * l32);
        const uint2 bm = *(const uint2*)(rel_msg  + (size_t)relo * 128 + 4 * l32);
        const uint2 tm = *(const uint2*)(dt_msg   + (size_t)dio  * 128 + 4 * l32);
        a0 += alo * (blo(am.x) + blo(bm.x) + blo(tm.x));
        a1 += alo * (bhi(am.x) + bhi(bm.x) + bhi(tm.x));
        a2 += alo * (blo(am.y) + blo(bm.y) + blo(tm.y));
        a3 += alo * (bhi(am.y) + bhi(bm.y) + bhi(tm.y));
    }

    a0 += __shfl_xor(a0, 32, 64);
    a1 += __shfl_xor(a1, 32, 64);
    a2 += __shfl_xor(a2, 32, 64);
    a3 += __shfl_xor(a3, 32, 64);

    if (half == 0) {
        float4 o; o.x = a0; o.y = a1; o.z = a2; o.w = a3;
        *(float4*)(out + (size_t)n * OUT_DIM + 4 * l32) = o;
    }
}

// ---------------------------------------------------------------------------
// Fallback: single-pass atomic edge kernel (small-workspace path).
// ---------------------------------------------------------------------------
__global__ __launch_bounds__(256) void edge_atomic_kernel(
    const int* __restrict__ edges, const int* __restrict__ q_tau,
    const ushort_t* __restrict__ node_attn, const ushort_t* __restrict__ node_msg,
    const ushort_t* __restrict__ rel_attn,  const ushort_t* __restrict__ rel_msg,
    const ushort_t* __restrict__ dt_attn,   const ushort_t* __restrict__ dt_msg,
    const ushort_t* __restrict__ Xqr,
    const float* __restrict__ w_alpha_W, const float* __restrict__ w_alpha_b,
    const int* __restrict__ flag, float* __restrict__ out)
{
    const int lane = threadIdx.x & 63;
    const int e    = blockIdx.x * 4 + (threadIdx.x >> 6);
    const int i64  = flag[0];

    int r, rel, tau, sub, obj;
    parse_edge(edges, e, i64, r, rel, tau, sub, obj);
    const int tq = q_tau[i64 ? 2 * r : r];
    if (tau < 0) tau = tq;
    const int di = clampi(tau - tq + 365, 0, N_DT - 1);

    const float xs = bu2f(node_attn[(size_t)sub * ATTN_DIM + lane]);
    const float xr = bu2f(rel_attn[(size_t)rel * ATTN_DIM + lane]);
    const float xt = bu2f(dt_attn[(size_t)di  * ATTN_DIM + lane]);
    const float xq = bu2f(Xqr[(size_t)r * ATTN_DIM + lane]);

    float v = fmaxf(xs + xr + xq + xt, 0.f) * w_alpha_W[lane];
    #pragma unroll
    for (int off = 32; off > 0; off >>= 1)
        v += __shfl_down(v, off, 64);
    v = __shfl(v, 0, 64);
    const float alpha = 1.f / (1.f + __expf(-(v + w_alpha_b[0])));

    const uint_t am = *(const uint_t*)(node_msg + (size_t)sub * 128 + 2 * lane);
    const uint_t bm = *(const uint_t*)(rel_msg  + (size_t)rel * 128 + 2 * lane);
    const uint_t tm = *(const uint_t*)(dt_msg   + (size_t)di  * 128 + 2 * lane);
    const float mx = blo(am) + blo(bm) + blo(tm);
    const float my = bhi(am) + bhi(bm) + bhi(tm);

    float* dst = out + (size_t)obj * OUT_DIM;
    atomicAdd(dst + 2 * lane,     alpha * mx);
    atomicAdd(dst + 2 * lane + 1, alpha * my);
}

// ===========================================================================
extern "C" void kernel_launch(void* const* d_in, const int* in_sizes, int n_in,
                              void* d_out, int out_size, void* d_ws, size_t ws_size,
                              hipStream_t stream)
{
    const int*   q_rel  = (const int*)d_in[1];
    const int*   q_tau  = (const int*)d_in[2];
    const float* hidden = (const float*)d_in[3];
    const int*   edges  = (const int*)d_in[4];
    const float* rela   = (const float*)d_in[7];
    const float* Ws     = (const float*)d_in[8];
    const float* Wr     = (const float*)d_in[9];
    const float* WqrW   = (const float*)d_in[10];
    const float* Wqrb   = (const float*)d_in[11];
    const float* Wtau   = (const float*)d_in[12];
    const float* waW    = (const float*)d_in[13];
    const float* wab    = (const float*)d_in[14];
    const float* Wh     = (const float*)d_in[15];
    const float* wt1    = (const float*)d_in[16];
    const float* bt1    = (const float*)d_in[17];
    const float* wt2    = (const float*)d_in[18];
    const float* bt2    = (const float*)d_in[19];
    float* out = (float*)d_out;

    // --- workspace carve (256-B aligned chunks) ---
    char* p = (char*)d_ws;
    size_t off = 0;
    auto carve = [&](size_t bytes) {
        char* q = p + off;
        off = (off + bytes + 255) & ~(size_t)255;
        return q;
    };
    int*      flag      = (int*)     carve(64);
    int*      cnt       = (int*)     carve((size_t)N_NODE * 4);
    int*      ovfn      = (int*)     carve(64);
    ushort_t* XqrB      = (ushort_t*)carve((size_t)N_QUERY * ATTN_DIM * 2);
    ushort_t* rel_attn  = (ushort_t*)carve((size_t)N_RELV * ATTN_DIM * 2);
    ushort_t* rel_msg   = (ushort_t*)carve((size_t)N_RELV * OUT_DIM * 2);
    ushort_t* dt_attn   = (ushort_t*)carve((size_t)N_DT * ATTN_DIM * 2);
    ushort_t* dt_msg    = (ushort_t*)carve((size_t)N_DT * OUT_DIM * 2);
    ushort_t* node_attn = (ushort_t*)carve((size_t)N_NODE * ATTN_DIM * 2);
    ushort_t* node_msg  = (ushort_t*)carve((size_t)N_NODE * OUT_DIM * 2);
    int2*     meta      = (int2*)    carve((size_t)N_NODE * CAP * 8);
    int4*     ovfl      = (int4*)    carve((size_t)N_EDGE * 16);
    const size_t need_full = off;

    fused_pre<<<NB_TOT, 256, 0, stream>>>(
        hidden, Ws, Wh, rela, Wr, Wtau, wt1, bt1, wt2, bt2,
        q_rel, WqrW, Wqrb, edges,
        node_attn, node_msg, rel_attn, rel_msg, dt_attn, dt_msg, XqrB,
        flag, cnt, ovfn);

    if (ws_size >= need_full) {
        alpha_scatter<<<(N_EDGE + 127) / 128, 256, 0, stream>>>(
            edges, q_tau, node_attn, rel_attn, dt_attn, XqrB,
            waW, wab, flag, cnt, meta, ovfn, ovfl);
        agg_kernel<<<N_NODE / 4, 256, 0, stream>>>(cnt, meta, ovfn, ovfl,
                                                   node_msg, rel_msg, dt_msg, out);
    } else {
        (void)hipMemsetAsync(out, 0, (size_t)out_size * sizeof(float), stream);
        edge_atomic_kernel<<<N_EDGE / 4, 256, 0, stream>>>(edges, q_tau,
                                                           node_attn, node_msg,
                                                           rel_attn, rel_msg,
                                                           dt_attn, dt_msg, XqrB,
                                                           waW, wab, flag, out);
    }
}

// Round 4
// 197.799 us; speedup vs baseline: 1.4593x; 1.0120x over previous
//
#include <hip/hip_runtime.h>
#include <hip/hip_fp16.h>

#define IN_DIM   128
#define OUT_DIM  128
#define ATTN_DIM 64
#define N_RELV   401
#define N_NODE   50000
#define N_EDGE   500000
#define N_QUERY  64
#define N_DT     731
#define CAP      40       // padded bucket capacity (deg ~ Poisson(10); P(>=40) ~ 1e-11)

// fused_pre block roles
#define NBW_NODE 782              // ceil(50000/64)
#define NBW_REL  7                // 7*64 = 448 >= 401
#define NBW_DT   12               // 12*64 = 768 >= 731
#define NBW_QR   1                // 64 queries
#define NBW_ZERO 13               // cnt zeroing
#define RB0      NBW_NODE
#define DB0      (NBW_NODE + NBW_REL)
#define QB0      (DB0 + NBW_DT)
#define ZB0      (QB0 + NBW_QR)
#define FB0      (ZB0 + NBW_ZERO)
#define NB_TOT   (FB0 + 1)

typedef unsigned short ushort_t;
typedef unsigned int   uint_t;
typedef __attribute__((ext_vector_type(8))) short v8s;   // 8 bf16 (4 VGPRs)
typedef __attribute__((ext_vector_type(4))) float v4f;

__device__ __forceinline__ int clampi(int v, int lo, int hi) {
    return v < lo ? lo : (v > hi ? hi : v);
}
__device__ __forceinline__ float bu2f(ushort_t u) {
    union { uint_t i; float f; } v; v.i = ((uint_t)u) << 16; return v.f;
}
__device__ __forceinline__ float blo(uint_t u) { return bu2f((ushort_t)(u & 0xffff)); }
__device__ __forceinline__ float bhi(uint_t u) { return bu2f((ushort_t)(u >> 16)); }
__device__ __forceinline__ ushort_t f2bu(float f) {   // RNE, finite inputs
    union { float f; uint_t i; } v; v.f = f;
    const uint_t x = v.i;
    return (ushort_t)((x + 0x7fffu + ((x >> 16) & 1u)) >> 16);
}
// packed RNE f32x2 -> bf16x2 (low = a, high = b)
__device__ __forceinline__ uint_t cvtpk(float a, float b) {
    uint_t r;
    asm("v_cvt_pk_bf16_f32 %0, %1, %2" : "=v"(r) : "v"(a), "v"(b));
    return r;
}

// LDS weight-table swizzle: logical (row, byte-in-row) -> banked offset.
// XOR bits 4..6 with row&7: ds_read_b128 per fragment becomes 2-way (free).
__device__ __forceinline__ int swz_byte(int row, int byte_in_row) {
    return (row * 256 + byte_in_row) ^ ((row & 7) << 4);
}

// stage W[128][64] transposed+bf16 into LDS rows 0..63   (attn weights)
__device__ __forceinline__ void stage_w64(ushort_t* shw, const float* __restrict__ W,
                                          int tid) {
    #pragma unroll
    for (int i = 0; i < 4; ++i) {
        const int pi = tid + 256 * i;
        const int kp = pi >> 4;              // col pair 0..63
        const int n4 = (pi & 15) * 4;        // row group
        const float4 A = *(const float4*)(W + (size_t)(2 * kp) * 64 + n4);
        const float4 B = *(const float4*)(W + (size_t)(2 * kp + 1) * 64 + n4);
        const float Aa[4] = {A.x, A.y, A.z, A.w};
        const float Ba[4] = {B.x, B.y, B.z, B.w};
        #pragma unroll
        for (int j = 0; j < 4; ++j)
            *(uint_t*)((char*)shw + swz_byte(n4 + j, kp * 4)) = cvtpk(Aa[j], Ba[j]);
    }
}
// stage W[128][128] transposed+bf16 into LDS rows 64..191 (msg weights)
__device__ __forceinline__ void stage_w128(ushort_t* shw, const float* __restrict__ W,
                                           int tid) {
    #pragma unroll
    for (int i = 0; i < 8; ++i) {
        const int pi = tid + 256 * i;
        const int kp = pi >> 5;              // col pair 0..63
        const int n4 = (pi & 31) * 4;        // row group 0..124
        const float4 A = *(const float4*)(W + (size_t)(2 * kp) * 128 + n4);
        const float4 B = *(const float4*)(W + (size_t)(2 * kp + 1) * 128 + n4);
        const float Aa[4] = {A.x, A.y, A.z, A.w};
        const float Ba[4] = {B.x, B.y, B.z, B.w};
        #pragma unroll
        for (int j = 0; j < 4; ++j)
            *(uint_t*)((char*)shw + swz_byte(64 + n4 + j, kp * 4)) = cvtpk(Aa[j], Ba[j]);
    }
}
// B-fragments for one fp32 row (this lane's table row), k-chunks by q
__device__ __forceinline__ void load_x_rows(const float* __restrict__ X, int rowc,
                                            int q, v8s hfr[4]) {
    #pragma unroll
    for (int c = 0; c < 4; ++c) {
        const float4 f0 = *(const float4*)(X + (size_t)rowc * 128 + 32 * c + 8 * q);
        const float4 f1 = *(const float4*)(X + (size_t)rowc * 128 + 32 * c + 8 * q + 4);
        union { v8s s; uint4 u; } uu;
        uu.u = make_uint4(cvtpk(f0.x, f0.y), cvtpk(f0.z, f0.w),
                          cvtpk(f1.x, f1.y), cvtpk(f1.z, f1.w));
        hfr[c] = uu.s;
    }
}
// full 192-dim MFMA + guarded packed store (attn rows 0..63, msg rows 64..191)
__device__ __forceinline__ void mfma_store(const ushort_t* shw, const v8s hfr[4],
                                           int row, int Nlim,
                                           ushort_t* __restrict__ attn_out,
                                           ushort_t* __restrict__ msg_out,
                                           int m16, int q) {
    #pragma unroll
    for (int t = 0; t < 12; ++t) {
        v4f acc = {0.f, 0.f, 0.f, 0.f};
        #pragma unroll
        for (int c = 0; c < 4; ++c) {
            const v8s wfr = *(const v8s*)((const char*)shw +
                              swz_byte(16 * t + m16, (32 * c + 8 * q) * 2));
            acc = __builtin_amdgcn_mfma_f32_16x16x32_bf16(wfr, hfr[c], acc, 0, 0, 0);
        }
        if (row < Nlim) {
            const uint_t u0 = cvtpk(acc[0], acc[1]);
            const uint_t u1 = cvtpk(acc[2], acc[3]);
            const int dim = 16 * t + 4 * q;
            if (dim < 64)
                *(uint2*)(attn_out + (size_t)row * 64 + dim) = make_uint2(u0, u1);
            else
                *(uint2*)(msg_out + (size_t)row * 128 + (dim - 64)) = make_uint2(u0, u1);
        }
    }
}

// ---------------------------------------------------------------------------
// fused_pre: one kernel, six block roles, all matmul work on MFMA.
// ---------------------------------------------------------------------------
__global__ __launch_bounds__(256) void fused_pre(
    const float* __restrict__ hidden, const float* __restrict__ Ws,
    const float* __restrict__ Wh,   const float* __restrict__ rela,
    const float* __restrict__ Wr,   const float* __restrict__ Wtau,
    const float* __restrict__ wt1,  const float* __restrict__ bt1,
    const float* __restrict__ wt2,  const float* __restrict__ bt2,
    const int* __restrict__ q_rel,  const float* __restrict__ WqrW,
    const float* __restrict__ Wqrb, const int* __restrict__ edges,
    ushort_t* __restrict__ node_attn, ushort_t* __restrict__ node_msg,
    ushort_t* __restrict__ rel_attn,  ushort_t* __restrict__ rel_msg,
    ushort_t* __restrict__ dt_attn,   ushort_t* __restrict__ dt_msg,
    ushort_t* __restrict__ Xqr,
    int* __restrict__ flag, int* __restrict__ cnt, int* __restrict__ ovfn)
{
    __shared__ ushort_t shw[192 * 128];          // 48 KiB
    const int bid = blockIdx.x, tid = threadIdx.x;
    const int wid = tid >> 6, lane = tid & 63;
    const int m16 = lane & 15, q = lane >> 4;

    if (bid < NBW_NODE) {
        stage_w64 (shw, Ws, tid);
        stage_w128(shw, Wh, tid);
        __syncthreads();
        const int row  = bid * 64 + wid * 16 + m16;
        const int rowc = row < N_NODE ? row : N_NODE - 1;
        v8s hfr[4];
        load_x_rows(hidden, rowc, q, hfr);
        mfma_store(shw, hfr, row, N_NODE, node_attn, node_msg, m16, q);
    } else if (bid < DB0) {
        stage_w64 (shw, Wr, tid);
        stage_w128(shw, Wh, tid);
        __syncthreads();
        const int row  = (bid - RB0) * 64 + wid * 16 + m16;
        const int rowc = row < N_RELV ? row : N_RELV - 1;
        v8s hfr[4];
        load_x_rows(rela, rowc, q, hfr);
        mfma_store(shw, hfr, row, N_RELV, rel_attn, rel_msg, m16, q);
    } else if (bid < QB0) {
        stage_w64 (shw, Wtau, tid);
        stage_w128(shw, Wh, tid);
        __syncthreads();
        const int row  = (bid - DB0) * 64 + wid * 16 + m16;
        const int rowc = row < N_DT ? row : N_DT - 1;
        const float dtv = (float)(rowc - 365);
        v8s hfr[4];
        #pragma unroll
        for (int c = 0; c < 4; ++c) {
            const int o = 32 * c + 8 * q;
            const float4 w1a = *(const float4*)(wt1 + o), w1b = *(const float4*)(wt1 + o + 4);
            const float4 b1a = *(const float4*)(bt1 + o), b1b = *(const float4*)(bt1 + o + 4);
            const float4 w2a = *(const float4*)(wt2 + o), w2b = *(const float4*)(wt2 + o + 4);
            const float4 b2a = *(const float4*)(bt2 + o), b2b = *(const float4*)(bt2 + o + 4);
            const float h0 = w1a.x * dtv + b1a.x + sinf(w2a.x * dtv + b2a.x);
            const float h1 = w1a.y * dtv + b1a.y + sinf(w2a.y * dtv + b2a.y);
            const float h2 = w1a.z * dtv + b1a.z + sinf(w2a.z * dtv + b2a.z);
            const float h3 = w1a.w * dtv + b1a.w + sinf(w2a.w * dtv + b2a.w);
            const float h4 = w1b.x * dtv + b1b.x + sinf(w2b.x * dtv + b2b.x);
            const float h5 = w1b.y * dtv + b1b.y + sinf(w2b.y * dtv + b2b.y);
            const float h6 = w1b.z * dtv + b1b.z + sinf(w2b.z * dtv + b2b.z);
            const float h7 = w1b.w * dtv + b1b.w + sinf(w2b.w * dtv + b2b.w);
            union { v8s s; uint4 u; } uu;
            uu.u = make_uint4(cvtpk(h0, h1), cvtpk(h2, h3), cvtpk(h4, h5), cvtpk(h6, h7));
            hfr[c] = uu.s;
        }
        mfma_store(shw, hfr, row, N_DT, dt_attn, dt_msg, m16, q);
    } else if (bid < ZB0) {
        // Xqr role (single block): local i64 detect, then attn-only MFMA + bias
        int* ok = (int*)shw;
        if (tid == 0) *ok = 1;
        __syncthreads();
        int badv = 0;
        for (int t = tid; t < 1000; t += 256) {
            const int w = edges[2 * t + 1];
            if (w != 0 && w != -1) badv = 1;
        }
        if (badv) *ok = 0;                       // benign race (all write 0)
        __syncthreads();
        const int i64 = *ok;
        __syncthreads();

        stage_w64(shw, WqrW, tid);
        __syncthreads();
        const int qrow = wid * 16 + m16;         // 0..63, exact
        const int relq = clampi(q_rel[i64 ? 2 * qrow : qrow], 0, N_RELV - 1);
        v8s hfr[4];
        load_x_rows(rela, relq, q, hfr);
        #pragma unroll
        for (int t = 0; t < 4; ++t) {
            v4f acc = {0.f, 0.f, 0.f, 0.f};
            #pragma unroll
            for (int c = 0; c < 4; ++c) {
                const v8s wfr = *(const v8s*)((const char*)shw +
                                  swz_byte(16 * t + m16, (32 * c + 8 * q) * 2));
                acc = __builtin_amdgcn_mfma_f32_16x16x32_bf16(wfr, hfr[c], acc, 0, 0, 0);
            }
            const int dim = 16 * t + 4 * q;
            const float4 bi = *(const float4*)(Wqrb + dim);
            const uint_t u0 = cvtpk(acc[0] + bi.x, acc[1] + bi.y);
            const uint_t u1 = cvtpk(acc[2] + bi.z, acc[3] + bi.w);
            *(uint2*)(Xqr + (size_t)qrow * 64 + dim) = make_uint2(u0, u1);
        }
    } else if (bid < FB0) {
        // cnt zeroing: 13 blocks x 256 threads x 4 int4 (50000 % 4 == 0)
        int4* c4 = (int4*)cnt;
        const int b = (bid - ZB0) * 256 + tid;
        #pragma unroll
        for (int k = 0; k < 4; ++k) {
            const int i4 = b * 4 + k;
            if (i4 < N_NODE / 4) c4[i4] = make_int4(0, 0, 0, 0);
        }
    } else {
        // global i64 flag + ovfn zero
        int* ok = (int*)shw;
        if (tid == 0) *ok = 0;
        __syncthreads();
        int badv = 0;
        for (int t = tid; t < 1000; t += 256) {
            const int w = edges[2 * t + 1];
            if (w != 0 && w != -1) badv = 1;
        }
        if (badv) *ok = 1;
        __syncthreads();
        if (tid == 0) { flag[0] = (*ok == 0) ? 1 : 0; ovfn[0] = 0; }
    }
}

// relu-dot over this lane's 8 dims for one edge
__device__ __forceinline__ float dot8(uint4 xs, uint4 xr, uint4 xt, uint4 xq,
                                      float4 wA, float4 wB)
{
    float s0, s1, v;
    s0 = blo(xs.x) + blo(xr.x) + blo(xt.x) + blo(xq.x);
    s1 = bhi(xs.x) + bhi(xr.x) + bhi(xt.x) + bhi(xq.x);
    v  = fmaxf(s0, 0.f) * wA.x + fmaxf(s1, 0.f) * wA.y;
    s0 = blo(xs.y) + blo(xr.y) + blo(xt.y) + blo(xq.y);
    s1 = bhi(xs.y) + bhi(xr.y) + bhi(xt.y) + bhi(xq.y);
    v += fmaxf(s0, 0.f) * wA.z + fmaxf(s1, 0.f) * wA.w;
    s0 = blo(xs.z) + blo(xr.z) + blo(xt.z) + blo(xq.z);
    s1 = bhi(xs.z) + bhi(xr.z) + bhi(xt.z) + bhi(xq.z);
    v += fmaxf(s0, 0.f) * wB.x + fmaxf(s1, 0.f) * wB.y;
    s0 = blo(xs.w) + blo(xr.w) + blo(xt.w) + blo(xq.w);
    s1 = bhi(xs.w) + bhi(xr.w) + bhi(xt.w) + bhi(xq.w);
    v += fmaxf(s0, 0.f) * wB.z + fmaxf(s1, 0.f) * wB.w;
    return v;
}

// ---------------------------------------------------------------------------
// Phase 1: per-edge alpha. 8 lanes per edge, 4 edges per group (32/wave).
// i32 path: ONE int4 load per lane covers the group's 4 edge rows (28 ints);
// fields distributed via compile-time-indexed width-8 shfl (no redundant
// scalar parses). meta TRANSPOSED: meta[pos * N_NODE + obj] (int2).
// ---------------------------------------------------------------------------
__global__ __launch_bounds__(256) void alpha_scatter(
    const int* __restrict__ edges, const int* __restrict__ q_tau,
    const ushort_t* __restrict__ node_attn, const ushort_t* __restrict__ rel_attn,
    const ushort_t* __restrict__ dt_attn,  const ushort_t* __restrict__ Xqr,
    const float* __restrict__ w_alpha_W, const float* __restrict__ w_alpha_b,
    const int* __restrict__ flag, int* __restrict__ cnt,
    int2* __restrict__ meta, int* __restrict__ ovfn, int4* __restrict__ ovfl)
{
    const int g   = threadIdx.x & 7;
    const int grp = threadIdx.x >> 3;               // 0..31
    const int e0r = blockIdx.x * 128 + grp * 4;
    const int e0  = e0r <= N_EDGE - 4 ? e0r : N_EDGE - 4;   // stays 4-aligned
    const int i64 = flag[0];

    const float4 wA = *(const float4*)(w_alpha_W + 8 * g);
    const float4 wB = *(const float4*)(w_alpha_W + 8 * g + 4);

    int r0, rel0, tau0, sub0, obj0, r1, rel1, tau1, sub1, obj1;
    int r2, rel2, tau2, sub2, obj2, r3, rel3, tau3, sub3, obj3;
    if (!i64) {
        const int4 ev = *(const int4*)(edges + (size_t)e0 * 7 + 4 * (g < 6 ? g : 6));
        #define GETF(j) __shfl(((j) & 3) == 0 ? ev.x : ((j) & 3) == 1 ? ev.y : \
                               ((j) & 3) == 2 ? ev.z : ev.w, (j) >> 2, 8)
        r0 = GETF(0);  rel0 = GETF(2);  tau0 = GETF(4);  sub0 = GETF(5);  obj0 = GETF(6);
        r1 = GETF(7);  rel1 = GETF(9);  tau1 = GETF(11); sub1 = GETF(12); obj1 = GETF(13);
        r2 = GETF(14); rel2 = GETF(16); tau2 = GETF(18); sub2 = GETF(19); obj2 = GETF(20);
        r3 = GETF(21); rel3 = GETF(23); tau3 = GETF(25); sub3 = GETF(26); obj3 = GETF(27);
        #undef GETF
    } else {
        const int* E0 = edges + (size_t)(e0    ) * 14;
        const int* E1 = edges + (size_t)(e0 + 1) * 14;
        const int* E2 = edges + (size_t)(e0 + 2) * 14;
        const int* E3 = edges + (size_t)(e0 + 3) * 14;
        r0 = E0[0]; rel0 = E0[4]; tau0 = E0[8]; sub0 = E0[10]; obj0 = E0[12];
        r1 = E1[0]; rel1 = E1[4]; tau1 = E1[8]; sub1 = E1[10]; obj1 = E1[12];
        r2 = E2[0]; rel2 = E2[4]; tau2 = E2[8]; sub2 = E2[10]; obj2 = E2[12];
        r3 = E3[0]; rel3 = E3[4]; tau3 = E3[8]; sub3 = E3[10]; obj3 = E3[12];
    }
    r0 = clampi(r0, 0, N_QUERY - 1); rel0 = clampi(rel0, 0, N_RELV - 1);
    sub0 = clampi(sub0, 0, N_NODE - 1); obj0 = clampi(obj0, 0, N_NODE - 1);
    r1 = clampi(r1, 0, N_QUERY - 1); rel1 = clampi(rel1, 0, N_RELV - 1);
    sub1 = clampi(sub1, 0, N_NODE - 1); obj1 = clampi(obj1, 0, N_NODE - 1);
    r2 = clampi(r2, 0, N_QUERY - 1); rel2 = clampi(rel2, 0, N_RELV - 1);
    sub2 = clampi(sub2, 0, N_NODE - 1); obj2 = clampi(obj2, 0, N_NODE - 1);
    r3 = clampi(r3, 0, N_QUERY - 1); rel3 = clampi(rel3, 0, N_RELV - 1);
    sub3 = clampi(sub3, 0, N_NODE - 1); obj3 = clampi(obj3, 0, N_NODE - 1);

    const int tq0 = q_tau[i64 ? 2 * r0 : r0];
    const int tq1 = q_tau[i64 ? 2 * r1 : r1];
    const int tq2 = q_tau[i64 ? 2 * r2 : r2];
    const int tq3 = q_tau[i64 ? 2 * r3 : r3];
    if (tau0 < 0) tau0 = tq0;
    if (tau1 < 0) tau1 = tq1;
    if (tau2 < 0) tau2 = tq2;
    if (tau3 < 0) tau3 = tq3;
    const int di0 = clampi(tau0 - tq0 + 365, 0, N_DT - 1);
    const int di1 = clampi(tau1 - tq1 + 365, 0, N_DT - 1);
    const int di2 = clampi(tau2 - tq2 + 365, 0, N_DT - 1);
    const int di3 = clampi(tau3 - tq3 + 365, 0, N_DT - 1);

    // 16 independent gathers in flight
    const uint4 xs0 = *(const uint4*)(node_attn + (size_t)sub0 * ATTN_DIM + 8 * g);
    const uint4 xr0 = *(const uint4*)(rel_attn + (size_t)rel0 * ATTN_DIM + 8 * g);
    const uint4 xt0 = *(const uint4*)(dt_attn  + (size_t)di0  * ATTN_DIM + 8 * g);
    const uint4 xq0 = *(const uint4*)(Xqr      + (size_t)r0   * ATTN_DIM + 8 * g);
    const uint4 xs1 = *(const uint4*)(node_attn + (size_t)sub1 * ATTN_DIM + 8 * g);
    const uint4 xr1 = *(const uint4*)(rel_attn + (size_t)rel1 * ATTN_DIM + 8 * g);
    const uint4 xt1 = *(const uint4*)(dt_attn  + (size_t)di1  * ATTN_DIM + 8 * g);
    const uint4 xq1 = *(const uint4*)(Xqr      + (size_t)r1   * ATTN_DIM + 8 * g);
    const uint4 xs2 = *(const uint4*)(node_attn + (size_t)sub2 * ATTN_DIM + 8 * g);
    const uint4 xr2 = *(const uint4*)(rel_attn + (size_t)rel2 * ATTN_DIM + 8 * g);
    const uint4 xt2 = *(const uint4*)(dt_attn  + (size_t)di2  * ATTN_DIM + 8 * g);
    const uint4 xq2 = *(const uint4*)(Xqr      + (size_t)r2   * ATTN_DIM + 8 * g);
    const uint4 xs3 = *(const uint4*)(node_attn + (size_t)sub3 * ATTN_DIM + 8 * g);
    const uint4 xr3 = *(const uint4*)(rel_attn + (size_t)rel3 * ATTN_DIM + 8 * g);
    const uint4 xt3 = *(const uint4*)(dt_attn  + (size_t)di3  * ATTN_DIM + 8 * g);
    const uint4 xq3 = *(const uint4*)(Xqr      + (size_t)r3   * ATTN_DIM + 8 * g);

    float v0 = dot8(xs0, xr0, xt0, xq0, wA, wB);
    float v1 = dot8(xs1, xr1, xt1, xq1, wA, wB);
    float v2 = dot8(xs2, xr2, xt2, xq2, wA, wB);
    float v3 = dot8(xs3, xr3, xt3, xq3, wA, wB);

    #pragma unroll
    for (int off = 4; off > 0; off >>= 1) {
        v0 += __shfl_xor(v0, off, 8);
        v1 += __shfl_xor(v1, off, 8);
        v2 += __shfl_xor(v2, off, 8);
        v3 += __shfl_xor(v3, off, 8);
    }

    if (g < 4 && e0r + g < N_EDGE) {
        const float vg  = g == 0 ? v0 : (g == 1 ? v1 : (g == 2 ? v2 : v3));
        const int objg  = g == 0 ? obj0 : (g == 1 ? obj1 : (g == 2 ? obj2 : obj3));
        const int subg  = g == 0 ? sub0 : (g == 1 ? sub1 : (g == 2 ? sub2 : sub3));
        const int dig   = g == 0 ? di0  : (g == 1 ? di1  : (g == 2 ? di2  : di3));
        const int relg  = g == 0 ? rel0 : (g == 1 ? rel1 : (g == 2 ? rel2 : rel3));
        const float alpha = 1.f / (1.f + __expf(-(vg + w_alpha_b[0])));
        const int pos = atomicAdd(&cnt[objg], 1);
        if (pos < CAP) {
            const uint_t px = (uint_t)subg | ((uint_t)dig << 17) | ((uint_t)(relg & 31) << 27);
            const uint_t py = (uint_t)(relg >> 5) |
                              ((uint_t)__half_as_ushort(__float2half_rn(alpha)) << 16);
            meta[(size_t)pos * N_NODE + objg] = make_int2((int)px, (int)py);
        } else {
            const int ov = atomicAdd(ovfn, 1);
            if (ov < N_EDGE)
                ovfl[ov] = make_int4(subg | (dig << 17), relg | (objg << 9),
                                     __float_as_int(alpha), 0);
        }
    }
}

// ---------------------------------------------------------------------------
// Phase 2: per-node aggregation. Half-wave per edge, uint2 gathers,
// unroll 8 (24 gathers in flight), __shfl_xor(32) combine, float4 store.
// ---------------------------------------------------------------------------
__device__ __forceinline__ void agg_edge(
    int2 m, int l32,
    const ushort_t* __restrict__ node_msg, const ushort_t* __restrict__ rel_msg,
    const ushort_t* __restrict__ dt_msg,
    float& a0, float& a1, float& a2, float& a3)
{
    const int sub = m.x & 0x1FFFF;
    const int di  = ((uint_t)m.x >> 17) & 0x3FF;
    const int rel = (((uint_t)m.x >> 27) & 31) | (((uint_t)m.y & 0xF) << 5);
    const float al = __half2float(__ushort_as_half((ushort_t)((uint_t)m.y >> 16)));
    const uint2 am = *(const uint2*)(node_msg + (size_t)sub * 128 + 4 * l32);
    const uint2 bm = *(const uint2*)(rel_msg  + (size_t)rel * 128 + 4 * l32);
    const uint2 tm = *(const uint2*)(dt_msg   + (size_t)di  * 128 + 4 * l32);
    a0 += al * (blo(am.x) + blo(bm.x) + blo(tm.x));
    a1 += al * (bhi(am.x) + bhi(bm.x) + bhi(tm.x));
    a2 += al * (blo(am.y) + blo(bm.y) + blo(tm.y));
    a3 += al * (bhi(am.y) + bhi(bm.y) + bhi(tm.y));
}

__global__ __launch_bounds__(256) void agg_kernel(
    const int* __restrict__ cnt, const int2* __restrict__ meta,
    const int* __restrict__ ovfn, const int4* __restrict__ ovfl,
    const ushort_t* __restrict__ node_msg, const ushort_t* __restrict__ rel_msg,
    const ushort_t* __restrict__ dt_msg, float* __restrict__ out)
{
    const int lane = threadIdx.x & 63;
    const int half = lane >> 5;                  // 0/1: which edge of the pair
    const int l32  = lane & 31;                  // covers dims 4*l32..+3
    const int n    = blockIdx.x * 4 + (threadIdx.x >> 6);

    int m = cnt[n]; if (m > CAP) m = CAP;
    float a0 = 0.f, a1 = 0.f, a2 = 0.f, a3 = 0.f;

    int j = 0;
    for (; j + 7 < m; j += 8) {                  // 8 edges per iteration
        const int2 ma = meta[(size_t)(j     + half) * N_NODE + n];
        const int2 mb = meta[(size_t)(j + 2 + half) * N_NODE + n];
        const int2 mc = meta[(size_t)(j + 4 + half) * N_NODE + n];
        const int2 md = meta[(size_t)(j + 6 + half) * N_NODE + n];
        agg_edge(ma, l32, node_msg, rel_msg, dt_msg, a0, a1, a2, a3);
        agg_edge(mb, l32, node_msg, rel_msg, dt_msg, a0, a1, a2, a3);
        agg_edge(mc, l32, node_msg, rel_msg, dt_msg, a0, a1, a2, a3);
        agg_edge(md, l32, node_msg, rel_msg, dt_msg, a0, a1, a2, a3);
    }
    for (; j + 1 < m; j += 2) {                  // 2 edges
        const int2 ma = meta[(size_t)(j + half) * N_NODE + n];
        agg_edge(ma, l32, node_msg, rel_msg, dt_msg, a0, a1, a2, a3);
    }
    if (j < m && half == 0) {                    // odd tail: half 0 only
        const int2 ma = meta[(size_t)j * N_NODE + n];
        agg_edge(ma, l32, node_msg, rel_msg, dt_msg, a0, a1, a2, a3);
    }

    // overflow entries (normally none): scan, filter by obj == n, half 0 only
    int nov = ovfn[0]; if (nov > N_EDGE) nov = N_EDGE;
    for (int i = 0; i < nov; ++i) {
        const int4 mo = ovfl[i];
        const int objo = (int)((uint_t)mo.y >> 9);
        if (objo != n || half != 0) continue;
        const int subo = mo.x & 0x1FFFF;
        const int dio  = (int)((uint_t)mo.x >> 17);
        const int relo = mo.y & 0x1FF;
        const float alo = __int_as_float(mo.z);
        const uint2 am = *(const uint2*)(node_msg + (size_t)subo * 128 + 4 * l32);
        const uint2 bm = *(const uint2*)(rel_msg  + (size_t)relo * 128 + 4 * l32);
        const uint2 tm = *(const uint2*)(dt_msg   + (size_t)dio  * 128 + 4 * l32);
        a0 += alo * (blo(am.x) + blo(bm.x) + blo(tm.x));
        a1 += alo * (bhi(am.x) + bhi(bm.x) + bhi(tm.x));
        a2 += alo * (blo(am.y) + blo(bm.y) + blo(tm.y));
        a3 += alo * (bhi(am.y) + bhi(bm.y) + bhi(tm.y));
    }

    a0 += __shfl_xor(a0, 32, 64);
    a1 += __shfl_xor(a1, 32, 64);
    a2 += __shfl_xor(a2, 32, 64);
    a3 += __shfl_xor(a3, 32, 64);

    if (half == 0) {
        float4 o; o.x = a0; o.y = a1; o.z = a2; o.w = a3;
        *(float4*)(out + (size_t)n * OUT_DIM + 4 * l32) = o;
    }
}

// ---------------------------------------------------------------------------
// Fallback: single-pass atomic edge kernel (small-workspace path).
// ---------------------------------------------------------------------------
__device__ __forceinline__ void parse_edge(const int* __restrict__ edges, int e,
                                           int i64, int& r, int& rel, int& tau,
                                           int& sub, int& obj) {
    if (i64) {
        const int* E = edges + (size_t)e * 14;
        r = E[0]; rel = E[4]; tau = E[8]; sub = E[10]; obj = E[12];
    } else {
        const int* E = edges + (size_t)e * 7;
        r = E[0]; rel = E[2]; tau = E[4]; sub = E[5]; obj = E[6];
    }
    r   = clampi(r,   0, N_QUERY - 1);
    rel = clampi(rel, 0, N_RELV - 1);
    sub = clampi(sub, 0, N_NODE - 1);
    obj = clampi(obj, 0, N_NODE - 1);
}

__global__ __launch_bounds__(256) void edge_atomic_kernel(
    const int* __restrict__ edges, const int* __restrict__ q_tau,
    const ushort_t* __restrict__ node_attn, const ushort_t* __restrict__ node_msg,
    const ushort_t* __restrict__ rel_attn,  const ushort_t* __restrict__ rel_msg,
    const ushort_t* __restrict__ dt_attn,   const ushort_t* __restrict__ dt_msg,
    const ushort_t* __restrict__ Xqr,
    const float* __restrict__ w_alpha_W, const float* __restrict__ w_alpha_b,
    const int* __restrict__ flag, float* __restrict__ out)
{
    const int lane = threadIdx.x & 63;
    const int e    = blockIdx.x * 4 + (threadIdx.x >> 6);
    const int i64  = flag[0];

    int r, rel, tau, sub, obj;
    parse_edge(edges, e, i64, r, rel, tau, sub, obj);
    const int tq = q_tau[i64 ? 2 * r : r];
    if (tau < 0) tau = tq;
    const int di = clampi(tau - tq + 365, 0, N_DT - 1);

    const float xs = bu2f(node_attn[(size_t)sub * ATTN_DIM + lane]);
    const float xr = bu2f(rel_attn[(size_t)rel * ATTN_DIM + lane]);
    const float xt = bu2f(dt_attn[(size_t)di  * ATTN_DIM + lane]);
    const float xq = bu2f(Xqr[(size_t)r * ATTN_DIM + lane]);

    float v = fmaxf(xs + xr + xq + xt, 0.f) * w_alpha_W[lane];
    #pragma unroll
    for (int off = 32; off > 0; off >>= 1)
        v += __shfl_down(v, off, 64);
    v = __shfl(v, 0, 64);
    const float alpha = 1.f / (1.f + __expf(-(v + w_alpha_b[0])));

    const uint_t am = *(const uint_t*)(node_msg + (size_t)sub * 128 + 2 * lane);
    const uint_t bm = *(const uint_t*)(rel_msg  + (size_t)rel * 128 + 2 * lane);
    const uint_t tm = *(const uint_t*)(dt_msg   + (size_t)di  * 128 + 2 * lane);
    const float mx = blo(am) + blo(bm) + blo(tm);
    const float my = bhi(am) + bhi(bm) + bhi(tm);

    float* dst = out + (size_t)obj * OUT_DIM;
    atomicAdd(dst + 2 * lane,     alpha * mx);
    atomicAdd(dst + 2 * lane + 1, alpha * my);
}

// ===========================================================================
extern "C" void kernel_launch(void* const* d_in, const int* in_sizes, int n_in,
                              void* d_out, int out_size, void* d_ws, size_t ws_size,
                              hipStream_t stream)
{
    const int*   q_rel  = (const int*)d_in[1];
    const int*   q_tau  = (const int*)d_in[2];
    const float* hidden = (const float*)d_in[3];
    const int*   edges  = (const int*)d_in[4];
    const float* rela   = (const float*)d_in[7];
    const float* Ws     = (const float*)d_in[8];
    const float* Wr     = (const float*)d_in[9];
    const float* WqrW   = (const float*)d_in[10];
    const float* Wqrb   = (const float*)d_in[11];
    const float* Wtau   = (const float*)d_in[12];
    const float* waW    = (const float*)d_in[13];
    const float* wab    = (const float*)d_in[14];
    const float* Wh     = (const float*)d_in[15];
    const float* wt1    = (const float*)d_in[16];
    const float* bt1    = (const float*)d_in[17];
    const float* wt2    = (const float*)d_in[18];
    const float* bt2    = (const float*)d_in[19];
    float* out = (float*)d_out;

    // --- workspace carve (256-B aligned chunks) ---
    char* p = (char*)d_ws;
    size_t off = 0;
    auto carve = [&](size_t bytes) {
        char* q = p + off;
        off = (off + bytes + 255) & ~(size_t)255;
        return q;
    };
    int*      flag      = (int*)     carve(64);
    int*      cnt       = (int*)     carve((size_t)N_NODE * 4);
    int*      ovfn      = (int*)     carve(64);
    ushort_t* XqrB      = (ushort_t*)carve((size_t)N_QUERY * ATTN_DIM * 2);
    ushort_t* rel_attn  = (ushort_t*)carve((size_t)N_RELV * ATTN_DIM * 2);
    ushort_t* rel_msg   = (ushort_t*)carve((size_t)N_RELV * OUT_DIM * 2);
    ushort_t* dt_attn   = (ushort_t*)carve((size_t)N_DT * ATTN_DIM * 2);
    ushort_t* dt_msg    = (ushort_t*)carve((size_t)N_DT * OUT_DIM * 2);
    ushort_t* node_attn = (ushort_t*)carve((size_t)N_NODE * ATTN_DIM * 2);
    ushort_t* node_msg  = (ushort_t*)carve((size_t)N_NODE * OUT_DIM * 2);
    int2*     meta      = (int2*)    carve((size_t)N_NODE * CAP * 8);
    int4*     ovfl      = (int4*)    carve((size_t)N_EDGE * 16);
    const size_t need_full = off;

    fused_pre<<<NB_TOT, 256, 0, stream>>>(
        hidden, Ws, Wh, rela, Wr, Wtau, wt1, bt1, wt2, bt2,
        q_rel, WqrW, Wqrb, edges,
        node_attn, node_msg, rel_attn, rel_msg, dt_attn, dt_msg, XqrB,
        flag, cnt, ovfn);

    if (ws_size >= need_full) {
        alpha_scatter<<<(N_EDGE + 127) / 128, 256, 0, stream>>>(
            edges, q_tau, node_attn, rel_attn, dt_attn, XqrB,
            waW, wab, flag, cnt, meta, ovfn, ovfl);
        agg_kernel<<<N_NODE / 4, 256, 0, stream>>>(cnt, meta, ovfn, ovfl,
                                                   node_msg, rel_msg, dt_msg, out);
    } else {
        (void)hipMemsetAsync(out, 0, (size_t)out_size * sizeof(float), stream);
        edge_atomic_kernel<<<N_EDGE / 4, 256, 0, stream>>>(edges, q_tau,
                                                           node_attn, node_msg,
                                                           rel_attn, rel_msg,
                                                           dt_attn, dt_msg, XqrB,
                                                           waW, wab, flag, out);
    }
}